// Round 2
// baseline (1997.456 us; speedup 1.0000x reference)
//
#include <hip/hip_runtime.h>

#define TPB 256

typedef __attribute__((ext_vector_type(4))) float f32x4;
typedef __attribute__((ext_vector_type(8))) short s16x8;

__device__ __forceinline__ ushort f2bf(float f) {
  unsigned x = __float_as_uint(f);
  return (ushort)((x + 0x7fffu + ((x >> 16) & 1u)) >> 16);
}
__device__ __forceinline__ float b2f(ushort u) {
  return __uint_as_float(((unsigned)u) << 16);
}
__device__ __forceinline__ void gload_lds16(const ushort* g, ushort* l) {
  __builtin_amdgcn_global_load_lds(
      (const __attribute__((address_space(1))) void*)g,
      (__attribute__((address_space(3))) void*)l, 16, 0, 0);
}

__device__ __forceinline__ float blk_sum(float v, float* red, int tid) {
#pragma unroll
  for (int o = 32; o; o >>= 1) v += __shfl_xor(v, o);
  if ((tid & 63) == 0) red[tid >> 6] = v;
  __syncthreads();
  float r = red[0] + red[1] + red[2] + red[3];
  __syncthreads();
  return r;
}
__device__ __forceinline__ float blk_max(float v, float* red, int tid) {
#pragma unroll
  for (int o = 32; o; o >>= 1) v = fmaxf(v, __shfl_xor(v, o));
  if ((tid & 63) == 0) red[tid >> 6] = v;
  __syncthreads();
  float r = fmaxf(fmaxf(red[0], red[1]), fmaxf(red[2], red[3]));
  __syncthreads();
  return r;
}

// ---------------------------------------------------------------------------
// GEMM: C[M,N] = A[M,K](bf16) @ Bt[N,K]^T(bf16)  (+bias, +residual, or +=C)
// z-batched: offsets (z>>4)*s?b + (z&15)*s?h.  A rows shifted within 1024-row
// segments (conv taps); out-of-range rows read from the zeroed page `zp`.
// 128x128 tile (BN=64 variant for PV), BK=32, 4 waves 2x2, 16x16x32 bf16 MFMA.
// ---------------------------------------------------------------------------
template<int BN, bool C_BF16, bool ACCUM, bool HAS_BIAS, bool HAS_RES>
__global__ __launch_bounds__(TPB, 2)
void gemm_bt(const ushort* __restrict__ A, int lda, long sAb, long sAh,
             const ushort* __restrict__ B, int ldb, long sBb, long sBh,
             void* __restrict__ Cp, int ldc, long sCb, long sCh,
             const float* __restrict__ bias, const float* __restrict__ Res,
             int K, int shift, const ushort* __restrict__ zp)
{
  constexpr int BM = 128, BK = 32;
  constexpr int FN = BN / 32;              // frags per wave in N (128->4, 64->2)
  __shared__ ushort lA[BM * BK];
  __shared__ ushort lB[BN * BK];
  const int tid = threadIdx.x;
  const int zb = blockIdx.z >> 4, zh = blockIdx.z & 15;
  const ushort* Az = A + (long)zb * sAb + (long)zh * sAh;
  const ushort* Bz = B + (long)zb * sBb + (long)zh * sBh;
  const int rowBase = blockIdx.x * BM;
  const int colBase = blockIdx.y * BN;
  const int w = tid >> 6, lane = tid & 63;
  const int wr = w >> 1, wc = w & 1;
  const int lr = lane & 15, lk = (lane >> 4) * 8;

  f32x4 acc[4][FN] = {};

  for (int k0 = 0; k0 < K; k0 += BK) {
#pragma unroll
    for (int i = 0; i < BM * BK * 2 / 4096; ++i) {   // A: 8KB -> 2 issues
      int idx = i * TPB + tid;
      int r = idx >> 2, kk = (idx & 3) * 8;
      int gr = rowBase + r;
      int s = (gr & 1023) + shift;
      const ushort* src = ((unsigned)s < 1024u)
          ? (Az + (long)((gr & ~1023) + s) * lda + k0 + kk) : zp;
      gload_lds16(src, &lA[idx * 8]);
    }
#pragma unroll
    for (int i = 0; i < BN * BK * 2 / 4096; ++i) {   // B: 8KB (or 4KB) issues
      int idx = i * TPB + tid;
      int r = idx >> 2, kk = (idx & 3) * 8;
      gload_lds16(Bz + (long)(colBase + r) * ldb + k0 + kk, &lB[idx * 8]);
    }
    __syncthreads();
    s16x8 af[4], bfr[FN];
#pragma unroll
    for (int m = 0; m < 4; ++m)
      af[m] = *(const s16x8*)&lA[(wr * 64 + m * 16 + lr) * BK + lk];
#pragma unroll
    for (int n = 0; n < FN; ++n)
      bfr[n] = *(const s16x8*)&lB[(wc * (BN / 2) + n * 16 + lr) * BK + lk];
#pragma unroll
    for (int m = 0; m < 4; ++m)
#pragma unroll
      for (int n = 0; n < FN; ++n)
        acc[m][n] = __builtin_amdgcn_mfma_f32_16x16x32_bf16(af[m], bfr[n], acc[m][n], 0, 0, 0);
    __syncthreads();
  }

  const long zoffC = (long)zb * sCb + (long)zh * sCh;
  const int crow0 = rowBase + wr * 64 + (lane >> 4) * 4;
#pragma unroll
  for (int m = 0; m < 4; ++m) {
#pragma unroll
    for (int n = 0; n < FN; ++n) {
      const int ccol = colBase + wc * (BN / 2) + n * 16 + lr;
      const float bv = HAS_BIAS ? bias[ccol] : 0.f;
#pragma unroll
      for (int j = 0; j < 4; ++j) {
        const int row = crow0 + m * 16 + j;
        const long off = zoffC + (long)row * ldc + ccol;
        float v = acc[m][n][j] + bv;
        if (HAS_RES) v += Res[off];
        if (C_BF16)      ((ushort*)Cp)[off] = f2bf(v);
        else if (ACCUM)  ((float*)Cp)[off] += v;
        else             ((float*)Cp)[off] = v;
      }
    }
  }
}

// LayerNorm (torch variant: unbiased std, eps added to std). One block per row.
// Safe in-place (X == out): row fully read into registers before any write.
template<bool OBF>
__global__ __launch_bounds__(TPB)
void ln_rows(const float* __restrict__ X, const float* __restrict__ ga,
             const float* __restrict__ gb, void* __restrict__ out)
{
  __shared__ float red[4];
  const int tid = threadIdx.x;
  const long base = (long)blockIdx.x * 1024;
  f32x4 v = *(const f32x4*)&X[base + tid * 4];
  float mean = blk_sum(v[0] + v[1] + v[2] + v[3], red, tid) * (1.f / 1024.f);
  f32x4 d = v - mean;
  float qs = blk_sum(d[0]*d[0] + d[1]*d[1] + d[2]*d[2] + d[3]*d[3], red, tid);
  float inv = 1.f / (sqrtf(qs * (1.f / 1023.f)) + 1e-6f);
  f32x4 a4 = *(const f32x4*)&ga[tid * 4];
  f32x4 b4 = *(const f32x4*)&gb[tid * 4];
  f32x4 r = a4 * (d * inv) + b4;
  if (OBF) {
    ushort4 o4 = { f2bf(r[0]), f2bf(r[1]), f2bf(r[2]), f2bf(r[3]) };
    *(ushort4*)((ushort*)out + base + tid * 4) = o4;
  } else {
    *(f32x4*)((float*)out + base + tid * 4) = r;
  }
}

// Row softmax over 1024 cols, scale 1/8 folded into the exponent (softmax(s/8)).
__global__ __launch_bounds__(TPB)
void softmax_rows(ushort* __restrict__ S)
{
  __shared__ float red[4];
  const int tid = threadIdx.x;
  const long base = (long)blockIdx.x * 1024 + tid * 4;
  ushort4 u = *(const ushort4*)&S[base];
  float s0 = b2f(u.x), s1 = b2f(u.y), s2 = b2f(u.z), s3 = b2f(u.w);
  float mx = blk_max(fmaxf(fmaxf(s0, s1), fmaxf(s2, s3)), red, tid);
  const float c = 0.18033688f;  // log2(e)/8
  float e0 = exp2f((s0 - mx) * c), e1 = exp2f((s1 - mx) * c);
  float e2 = exp2f((s2 - mx) * c), e3 = exp2f((s3 - mx) * c);
  float inv = 1.f / blk_sum(e0 + e1 + e2 + e3, red, tid);
  ushort4 o4 = { f2bf(e0 * inv), f2bf(e1 * inv), f2bf(e2 * inv), f2bf(e3 * inv) };
  *(ushort4*)&S[base] = o4;
}

// vt[b*16+h][d=64][kv=1024] = qkv[(b*1024+kv)*3072 + 2048 + h*64 + d]
// grid: (16 kv-tiles, nb*16 bh)
__global__ __launch_bounds__(TPB)
void vt_build(const ushort* __restrict__ qkv, ushort* __restrict__ vt)
{
  __shared__ ushort t[64][72];
  const int tid = threadIdx.x;
  const int bh = blockIdx.y, b = bh >> 4, h = bh & 15;
  const int kv0 = blockIdx.x * 64;
#pragma unroll
  for (int it = 0; it < 2; ++it) {
    int idx = (it * TPB + tid) * 8;
    int r = idx >> 6, cc = idx & 63;
    s16x8 v = *(const s16x8*)(qkv + ((long)((b << 10) + kv0 + r)) * 3072 + 2048 + (h << 6) + cc);
#pragma unroll
    for (int j = 0; j < 8; ++j) t[r][cc + j] = (ushort)v[j];
  }
  __syncthreads();
#pragma unroll
  for (int it = 0; it < 2; ++it) {
    int idx = (it * TPB + tid) * 8;
    int dd = idx >> 6, kvo = idx & 63;
    ushort tmp[8];
#pragma unroll
    for (int j = 0; j < 8; ++j) tmp[j] = t[kvo + j][dd];
    *(s16x8*)(vt + ((long)bh * 64 + dd) * 1024 + kv0 + kvo) = *(const s16x8*)tmp;
  }
}

// x += relu(y*sc + sh) / 3   (one conv branch folded into the residual stream)
__global__ __launch_bounds__(TPB)
void bn_relu_acc(float* __restrict__ x, const float* __restrict__ y,
                 const float* __restrict__ sc, const float* __restrict__ sh)
{
  const long i = ((long)blockIdx.x * TPB + threadIdx.x) * 4;
  const int col = (int)(i & 1023);
  f32x4 yv = *(const f32x4*)&y[i];
  f32x4 r = yv * *(const f32x4*)&sc[col] + *(const f32x4*)&sh[col];
  f32x4 xo = *(const f32x4*)&x[i];
#pragma unroll
  for (int j = 0; j < 4; ++j) xo[j] += fmaxf(r[j], 0.f) * (1.f / 3.f);
  *(f32x4*)&x[i] = xo;
}

// weight prep ---------------------------------------------------------------
__global__ __launch_bounds__(TPB)
void wt_build(const float* __restrict__ in, ushort* __restrict__ out)
{ // out[n*1024+k] = bf16(in[k*1024+n])   (1024x1024)
  long idx = (long)blockIdx.x * TPB + threadIdx.x;
  int n = (int)(idx >> 10), k = (int)(idx & 1023);
  out[idx] = f2bf(in[((long)k << 10) + n]);
}
__global__ __launch_bounds__(TPB)
void tap_build(const float* __restrict__ w, ushort* __restrict__ out, int f)
{ // out[t][o*1024+i] = bf16(w[(o*1024+i)*f + t])
  long idx = (long)blockIdx.x * TPB + threadIdx.x;
  long oi = idx & 1048575; int t = (int)(idx >> 20);
  out[idx] = f2bf(w[oi * f + t]);
}
__global__ __launch_bounds__(TPB)
void bn_prep(const float* __restrict__ cb, const float* __restrict__ g,
             const float* __restrict__ bb, const float* __restrict__ m,
             const float* __restrict__ v, float* __restrict__ sc, float* __restrict__ sh)
{
  int i = blockIdx.x * TPB + threadIdx.x;
  float s = g[i] * rsqrtf(v[i] + 1e-5f);
  sc[i] = s;
  sh[i] = (cb[i] - m[i]) * s + bb[i];
}
__global__ __launch_bounds__(TPB)
void qkvb_build(const float* __restrict__ bq, const float* __restrict__ bk,
                const float* __restrict__ bv, float* __restrict__ out)
{
  int i = blockIdx.x * TPB + threadIdx.x;
  out[i] = (i < 1024) ? bq[i] : (i < 2048 ? bk[i - 1024] : bv[i - 2048]);
}
__global__ void zero_ws(ushort* z) { z[threadIdx.x] = 0; }

// ---------------------------------------------------------------------------
extern "C" void kernel_launch(void* const* d_in, const int* in_sizes, int n_in,
                              void* d_out, int out_size, void* d_ws, size_t ws_size,
                              hipStream_t stream)
{
  const float* X  = (const float*)d_in[0];
  const float* Wq = (const float*)d_in[1];
  const float* Wk = (const float*)d_in[2];
  const float* Wv = (const float*)d_in[3];
  const float* Wo = (const float*)d_in[4];
  const float* Bq = (const float*)d_in[5];
  const float* Bk = (const float*)d_in[6];
  const float* Bv = (const float*)d_in[7];
  const float* Bo = (const float*)d_in[8];
  const float *CW[3], *CB[3], *BG[3], *BBe[3], *BMu[3], *BVa[3];
  for (int i = 0; i < 3; ++i) {
    CW[i]  = (const float*)d_in[9 + 6 * i];
    CB[i]  = (const float*)d_in[10 + 6 * i];
    BG[i]  = (const float*)d_in[11 + 6 * i];
    BBe[i] = (const float*)d_in[12 + 6 * i];
    BMu[i] = (const float*)d_in[13 + 6 * i];
    BVa[i] = (const float*)d_in[14 + 6 * i];
  }
  const float* L1a = (const float*)d_in[27];
  const float* L2a = (const float*)d_in[28];
  const float* LFa = (const float*)d_in[29];
  const float* L1b = (const float*)d_in[30];
  const float* L2b = (const float*)d_in[31];
  const float* LFb = (const float*)d_in[32];

  // ------ workspace layout (diet: previous 314MB overflowed ws_size) ------
  char* p = (char*)d_ws;
  auto carve = [&](size_t bytes) { char* r = p; p += (bytes + 255) & ~(size_t)255; return r; };
  ushort* abuf  = (ushort*)carve(16777216);   // LN out bf16; tierA: also attn-out
  ushort* wqkvt = (ushort*)carve(6291456);
  ushort* wot   = (ushort*)carve(2097152);
  ushort* wtap  = (ushort*)carve(18874368);   // 9 taps [1024,1024] bf16
  float*  qkvb  = (float*) carve(12288);
  float*  bnsc  = (float*) carve(12288);
  float*  bnsh  = (float*) carve(12288);
  ushort* zp    = (ushort*)carve(256);
  char*   ps    = p;                          // shared (phase-aliased) region
  const size_t Pbytes = (size_t)(ps - (char*)d_ws);
  const size_t avail  = ws_size > Pbytes ? ws_size - Pbytes : 0;
  const size_t NEED_A = 100663296;  // qkv 48M + vt 16M + scores(16 heads) 32M
  const size_t NEED_B = 50331648;   // obuf 16M + max(qkv1+vt1+scores4, y) 32M
  const bool tierA = avail >= NEED_A;
  if (!tierA && avail < NEED_B) return;       // cannot run at all

  float* xbuf = (float*)d_out;                // residual stream lives in d_out

  ushort *qkv, *vt, *scores, *obuf;
  float* y;
  if (tierA) {
    qkv    = (ushort*)ps;
    vt     = (ushort*)(ps + 50331648);
    scores = (ushort*)(ps + 67108864);
    obuf   = abuf;                            // LN1 out dead after QKV GEMM
    y      = (float*)ps;                      // conv phase aliases attn scratch
  } else {
    obuf   = (ushort*)ps;
    qkv    = (ushort*)(ps + 16777216);        // per-batch [1024][3072]
    vt     = (ushort*)(ps + 16777216 + 6291456);
    scores = (ushort*)(ps + 16777216 + 6291456 + 2097152);  // 4 heads
    y      = (float*)(ps + 16777216);         // aliases qkv/vt/scores
  }

  // per-call weight prep (graph-safe: identical work every call)
  wt_build<<<4096, TPB, 0, stream>>>(Wq, wqkvt);
  wt_build<<<4096, TPB, 0, stream>>>(Wk, wqkvt + 1048576);
  wt_build<<<4096, TPB, 0, stream>>>(Wv, wqkvt + 2097152);
  wt_build<<<4096, TPB, 0, stream>>>(Wo, wot);
  tap_build<<<4096, TPB, 0, stream>>>(CW[0], wtap, 1);
  tap_build<<<3 * 4096, TPB, 0, stream>>>(CW[1], wtap + 1048576, 3);
  tap_build<<<5 * 4096, TPB, 0, stream>>>(CW[2], wtap + 4 * 1048576, 5);
  for (int i = 0; i < 3; ++i)
    bn_prep<<<4, TPB, 0, stream>>>(CB[i], BG[i], BBe[i], BMu[i], BVa[i],
                                   bnsc + i * 1024, bnsh + i * 1024);
  qkvb_build<<<12, TPB, 0, stream>>>(Bq, Bk, Bv, qkvb);
  zero_ws<<<1, 128, 0, stream>>>(zp);

  const int tap0[3] = {0, 1, 4}, ntap[3] = {1, 3, 5};

  for (int L = 0; L < 2; ++L) {
    const float* xs = (L == 0) ? X : xbuf;
    // ---- x + MHA(LN1(x)) ----
    ln_rows<true><<<8192, TPB, 0, stream>>>(xs, L1a, L1b, abuf);
    if (tierA) {
      gemm_bt<128, true, false, true, false><<<dim3(64, 24, 1), TPB, 0, stream>>>(
          abuf, 1024, 0, 0, wqkvt, 1024, 0, 0, qkv, 3072, 0, 0, qkvb, nullptr, 1024, 0, zp);
      vt_build<<<dim3(16, 128), TPB, 0, stream>>>(qkv, vt);
      for (int b = 0; b < 8; ++b) {           // 1 batch (16 heads) per chunk
        const ushort* qb = qkv + (long)b * 3145728;
        gemm_bt<128, true, false, false, false><<<dim3(8, 8, 16), TPB, 0, stream>>>(
            qb, 3072, 0, 64, qb + 1024, 3072, 0, 64,
            scores, 1024, 0, 1048576, nullptr, nullptr, 64, 0, zp);
        softmax_rows<<<16384, TPB, 0, stream>>>(scores);
        gemm_bt<64, true, false, false, false><<<dim3(8, 1, 16), TPB, 0, stream>>>(
            scores, 1024, 0, 1048576, vt + (long)b * 1048576, 1024, 0, 65536,
            obuf + (long)b * 1048576, 1024, 0, 64, nullptr, nullptr, 1024, 0, zp);
      }
    } else {
      for (int b = 0; b < 8; ++b) {           // per-batch QKV + 4-head chunks
        gemm_bt<128, true, false, true, false><<<dim3(8, 24, 1), TPB, 0, stream>>>(
            abuf + (long)b * 1048576, 1024, 0, 0, wqkvt, 1024, 0, 0,
            qkv, 3072, 0, 0, qkvb, nullptr, 1024, 0, zp);
        vt_build<<<dim3(16, 16), TPB, 0, stream>>>(qkv, vt);
        for (int hc = 0; hc < 4; ++hc) {
          const ushort* qh = qkv + hc * 256;
          gemm_bt<128, true, false, false, false><<<dim3(8, 8, 4), TPB, 0, stream>>>(
              qh, 3072, 0, 64, qh + 1024, 3072, 0, 64,
              scores, 1024, 0, 1048576, nullptr, nullptr, 64, 0, zp);
          softmax_rows<<<4096, TPB, 0, stream>>>(scores);
          gemm_bt<64, true, false, false, false><<<dim3(8, 1, 4), TPB, 0, stream>>>(
              scores, 1024, 0, 1048576, vt + hc * 262144, 1024, 0, 65536,
              obuf + (long)b * 1048576 + hc * 256, 1024, 0, 64,
              nullptr, nullptr, 1024, 0, zp);
        }
      }
    }
    gemm_bt<128, false, false, true, true><<<dim3(64, 8, 1), TPB, 0, stream>>>(
        obuf, 1024, 0, 0, wot, 1024, 0, 0, xbuf, 1024, 0, 0, Bo, xs, 1024, 0, zp);
    // ---- x + FFN(LN2(x)) ----
    ln_rows<true><<<8192, TPB, 0, stream>>>(xbuf, L2a, L2b, abuf);
    for (int br = 0; br < 3; ++br) {
      for (int t = 0; t < ntap[br]; ++t) {
        const ushort* w = wtap + (long)(tap0[br] + t) * 1048576;
        const int shift = t - ntap[br] / 2;
        if (t == 0)
          gemm_bt<128, false, false, false, false><<<dim3(64, 8, 1), TPB, 0, stream>>>(
              abuf, 1024, 0, 0, w, 1024, 0, 0, y, 1024, 0, 0,
              nullptr, nullptr, 1024, shift, zp);
        else
          gemm_bt<128, false, true, false, false><<<dim3(64, 8, 1), TPB, 0, stream>>>(
              abuf, 1024, 0, 0, w, 1024, 0, 0, y, 1024, 0, 0,
              nullptr, nullptr, 1024, shift, zp);
      }
      bn_relu_acc<<<8192, TPB, 0, stream>>>(xbuf, y, bnsc + br * 1024, bnsh + br * 1024);
    }
  }
  ln_rows<false><<<8192, TPB, 0, stream>>>(xbuf, LFa, LFb, d_out);
}

// Round 3
// 1598.680 us; speedup vs baseline: 1.2494x; 1.2494x over previous
//
#include <hip/hip_runtime.h>

#define TPB 256

typedef __attribute__((ext_vector_type(4))) float f32x4;
typedef __attribute__((ext_vector_type(8))) short s16x8;

__device__ __forceinline__ ushort f2bf(float f) {
  unsigned x = __float_as_uint(f);
  return (ushort)((x + 0x7fffu + ((x >> 16) & 1u)) >> 16);
}
__device__ __forceinline__ float b2f(ushort u) {
  return __uint_as_float(((unsigned)u) << 16);
}
__device__ __forceinline__ void gload_lds16(const ushort* g, ushort* l) {
  __builtin_amdgcn_global_load_lds(
      (const __attribute__((address_space(1))) void*)g,
      (__attribute__((address_space(3))) void*)l, 16, 0, 0);
}

__device__ __forceinline__ float blk_sum(float v, float* red, int tid) {
#pragma unroll
  for (int o = 32; o; o >>= 1) v += __shfl_xor(v, o);
  if ((tid & 63) == 0) red[tid >> 6] = v;
  __syncthreads();
  float r = red[0] + red[1] + red[2] + red[3];
  __syncthreads();
  return r;
}
__device__ __forceinline__ float blk_max(float v, float* red, int tid) {
#pragma unroll
  for (int o = 32; o; o >>= 1) v = fmaxf(v, __shfl_xor(v, o));
  if ((tid & 63) == 0) red[tid >> 6] = v;
  __syncthreads();
  float r = fmaxf(fmaxf(red[0], red[1]), fmaxf(red[2], red[3]));
  __syncthreads();
  return r;
}

// ---------------------------------------------------------------------------
// GEMM: C[M,N] = A[M,K](bf16) @ Bt[N,K]^T(bf16)  (+bias, +residual, or +=C)
// z-batched: offsets (z>>4)*s?b + (z&15)*s?h.  A rows shifted within 1024-row
// segments (conv taps); out-of-range rows read from the zeroed page `zp`.
// 128x128 tile (BN=64 variant for PV), BK=32, 4 waves 2x2, 16x16x32 bf16 MFMA.
// ---------------------------------------------------------------------------
template<int BN, bool C_BF16, bool ACCUM, bool HAS_BIAS, bool HAS_RES>
__global__ __launch_bounds__(TPB, 2)
void gemm_bt(const ushort* __restrict__ A, int lda, long sAb, long sAh,
             const ushort* __restrict__ B, int ldb, long sBb, long sBh,
             void* __restrict__ Cp, int ldc, long sCb, long sCh,
             const float* __restrict__ bias, const float* __restrict__ Res,
             int K, int shift, const ushort* __restrict__ zp)
{
  constexpr int BM = 128, BK = 32;
  constexpr int FN = BN / 32;              // frags per wave in N (128->4, 64->2)
  __shared__ ushort lA[BM * BK];
  __shared__ ushort lB[BN * BK];
  const int tid = threadIdx.x;
  const int zb = blockIdx.z >> 4, zh = blockIdx.z & 15;
  const ushort* Az = A + (long)zb * sAb + (long)zh * sAh;
  const ushort* Bz = B + (long)zb * sBb + (long)zh * sBh;
  const int rowBase = blockIdx.x * BM;
  const int colBase = blockIdx.y * BN;
  const int w = tid >> 6, lane = tid & 63;
  const int wr = w >> 1, wc = w & 1;
  const int lr = lane & 15, lk = (lane >> 4) * 8;

  f32x4 acc[4][FN] = {};

  for (int k0 = 0; k0 < K; k0 += BK) {
#pragma unroll
    for (int i = 0; i < BM * BK * 2 / 4096; ++i) {   // A: 8KB -> 2 issues
      int idx = i * TPB + tid;
      int r = idx >> 2, kk = (idx & 3) * 8;
      int gr = rowBase + r;
      int s = (gr & 1023) + shift;
      const ushort* src = ((unsigned)s < 1024u)
          ? (Az + (long)((gr & ~1023) + s) * lda + k0 + kk) : zp;
      gload_lds16(src, &lA[idx * 8]);
    }
#pragma unroll
    for (int i = 0; i < BN * BK * 2 / 4096; ++i) {   // B: 8KB (or 4KB) issues
      int idx = i * TPB + tid;
      int r = idx >> 2, kk = (idx & 3) * 8;
      gload_lds16(Bz + (long)(colBase + r) * ldb + k0 + kk, &lB[idx * 8]);
    }
    __syncthreads();
    s16x8 af[4], bfr[FN];
#pragma unroll
    for (int m = 0; m < 4; ++m)
      af[m] = *(const s16x8*)&lA[(wr * 64 + m * 16 + lr) * BK + lk];
#pragma unroll
    for (int n = 0; n < FN; ++n)
      bfr[n] = *(const s16x8*)&lB[(wc * (BN / 2) + n * 16 + lr) * BK + lk];
#pragma unroll
    for (int m = 0; m < 4; ++m)
#pragma unroll
      for (int n = 0; n < FN; ++n)
        acc[m][n] = __builtin_amdgcn_mfma_f32_16x16x32_bf16(af[m], bfr[n], acc[m][n], 0, 0, 0);
    __syncthreads();
  }

  const long zoffC = (long)zb * sCb + (long)zh * sCh;
  const int crow0 = rowBase + wr * 64 + (lane >> 4) * 4;
#pragma unroll
  for (int m = 0; m < 4; ++m) {
#pragma unroll
    for (int n = 0; n < FN; ++n) {
      const int ccol = colBase + wc * (BN / 2) + n * 16 + lr;
      const float bv = HAS_BIAS ? bias[ccol] : 0.f;
#pragma unroll
      for (int j = 0; j < 4; ++j) {
        const int row = crow0 + m * 16 + j;
        const long off = zoffC + (long)row * ldc + ccol;
        float v = acc[m][n][j] + bv;
        if (HAS_RES) v += Res[off];
        if (C_BF16)      ((ushort*)Cp)[off] = f2bf(v);
        else if (ACCUM)  ((float*)Cp)[off] += v;
        else             ((float*)Cp)[off] = v;
      }
    }
  }
}

// ---------------------------------------------------------------------------
// Fused conv FFN: x += mean_br relu(bn_br(conv_br(A)))
// One dispatch per layer. K-loop runs 9 segments (branch,tap): effective
// K = 9216. Tap-sum stays in AGPRs; at branch boundaries (seg 0,3,8) fold
// acc through BN+ReLU into res regs. Epilogue: x += res/3 (single RMW).
// Segment s -> branch br = (s==0)?0:(s<=3?1:2), shift = s==0?0:(s<=3?s-2:s-6).
// ---------------------------------------------------------------------------
__global__ __launch_bounds__(TPB, 2)
void conv_fused(const ushort* __restrict__ A, const ushort* __restrict__ W,
                float* __restrict__ x, const float* __restrict__ sc,
                const float* __restrict__ sh, const ushort* __restrict__ zp)
{
  constexpr int BM = 128, BK = 32;
  __shared__ ushort lA[BM * BK];
  __shared__ ushort lB[128 * BK];
  const int tid = threadIdx.x;
  const int rowBase = blockIdx.x * BM;
  const int colBase = blockIdx.y * 128;
  const int w = tid >> 6, lane = tid & 63;
  const int wr = w >> 1, wc = w & 1;
  const int lr = lane & 15, lk = (lane >> 4) * 8;

  f32x4 acc[4][4] = {};
  f32x4 res[4][4] = {};

  for (int s = 0; s < 9; ++s) {
    const int shift = (s == 0) ? 0 : ((s <= 3) ? s - 2 : s - 6);
    const ushort* Wseg = W + (long)s * 1048576;
    for (int k0 = 0; k0 < 1024; k0 += BK) {
#pragma unroll
      for (int i = 0; i < 2; ++i) {
        int idx = i * TPB + tid;
        int r = idx >> 2, kk = (idx & 3) * 8;
        int gr = rowBase + r;
        int sr = (gr & 1023) + shift;
        const ushort* src = ((unsigned)sr < 1024u)
            ? (A + (long)((gr & ~1023) + sr) * 1024 + k0 + kk) : zp;
        gload_lds16(src, &lA[idx * 8]);
      }
#pragma unroll
      for (int i = 0; i < 2; ++i) {
        int idx = i * TPB + tid;
        int r = idx >> 2, kk = (idx & 3) * 8;
        gload_lds16(Wseg + (long)(colBase + r) * 1024 + k0 + kk, &lB[idx * 8]);
      }
      __syncthreads();
      s16x8 af[4], bfr[4];
#pragma unroll
      for (int m = 0; m < 4; ++m)
        af[m] = *(const s16x8*)&lA[(wr * 64 + m * 16 + lr) * BK + lk];
#pragma unroll
      for (int n = 0; n < 4; ++n)
        bfr[n] = *(const s16x8*)&lB[(wc * 64 + n * 16 + lr) * BK + lk];
#pragma unroll
      for (int m = 0; m < 4; ++m)
#pragma unroll
        for (int n = 0; n < 4; ++n)
          acc[m][n] = __builtin_amdgcn_mfma_f32_16x16x32_bf16(af[m], bfr[n], acc[m][n], 0, 0, 0);
      __syncthreads();
    }
    if (s == 0 || s == 3 || s == 8) {        // branch boundary: BN+ReLU fold
      const int br = (s == 0) ? 0 : (s == 3 ? 1 : 2);
#pragma unroll
      for (int n = 0; n < 4; ++n) {
        const int col = colBase + wc * 64 + n * 16 + lr;
        const float scv = sc[br * 1024 + col];
        const float shv = sh[br * 1024 + col];
#pragma unroll
        for (int m = 0; m < 4; ++m)
#pragma unroll
          for (int j = 0; j < 4; ++j) {
            res[m][n][j] += fmaxf(acc[m][n][j] * scv + shv, 0.f);
            acc[m][n][j] = 0.f;
          }
      }
    }
  }

  const int crow0 = rowBase + wr * 64 + (lane >> 4) * 4;
#pragma unroll
  for (int m = 0; m < 4; ++m)
#pragma unroll
    for (int n = 0; n < 4; ++n) {
      const int col = colBase + wc * 64 + n * 16 + lr;
#pragma unroll
      for (int j = 0; j < 4; ++j) {
        const long off = (long)(crow0 + m * 16 + j) * 1024 + col;
        x[off] += res[m][n][j] * (1.f / 3.f);
      }
    }
}

// LayerNorm (torch variant: unbiased std, eps added to std). One block per row.
// Safe in-place (X == out): row fully read into registers before any write.
template<bool OBF>
__global__ __launch_bounds__(TPB)
void ln_rows(const float* __restrict__ X, const float* __restrict__ ga,
             const float* __restrict__ gb, void* __restrict__ out)
{
  __shared__ float red[4];
  const int tid = threadIdx.x;
  const long base = (long)blockIdx.x * 1024;
  f32x4 v = *(const f32x4*)&X[base + tid * 4];
  float mean = blk_sum(v[0] + v[1] + v[2] + v[3], red, tid) * (1.f / 1024.f);
  f32x4 d = v - mean;
  float qs = blk_sum(d[0]*d[0] + d[1]*d[1] + d[2]*d[2] + d[3]*d[3], red, tid);
  float inv = 1.f / (sqrtf(qs * (1.f / 1023.f)) + 1e-6f);
  f32x4 a4 = *(const f32x4*)&ga[tid * 4];
  f32x4 b4 = *(const f32x4*)&gb[tid * 4];
  f32x4 r = a4 * (d * inv) + b4;
  if (OBF) {
    ushort4 o4 = { f2bf(r[0]), f2bf(r[1]), f2bf(r[2]), f2bf(r[3]) };
    *(ushort4*)((ushort*)out + base + tid * 4) = o4;
  } else {
    *(f32x4*)((float*)out + base + tid * 4) = r;
  }
}

// Row softmax over 1024 cols, scale 1/8 folded into the exponent (softmax(s/8)).
__global__ __launch_bounds__(TPB)
void softmax_rows(ushort* __restrict__ S)
{
  __shared__ float red[4];
  const int tid = threadIdx.x;
  const long base = (long)blockIdx.x * 1024 + tid * 4;
  ushort4 u = *(const ushort4*)&S[base];
  float s0 = b2f(u.x), s1 = b2f(u.y), s2 = b2f(u.z), s3 = b2f(u.w);
  float mx = blk_max(fmaxf(fmaxf(s0, s1), fmaxf(s2, s3)), red, tid);
  const float c = 0.18033688f;  // log2(e)/8
  float e0 = exp2f((s0 - mx) * c), e1 = exp2f((s1 - mx) * c);
  float e2 = exp2f((s2 - mx) * c), e3 = exp2f((s3 - mx) * c);
  float inv = 1.f / blk_sum(e0 + e1 + e2 + e3, red, tid);
  ushort4 o4 = { f2bf(e0 * inv), f2bf(e1 * inv), f2bf(e2 * inv), f2bf(e3 * inv) };
  *(ushort4*)&S[base] = o4;
}

// vt[b*16+h][d=64][kv=1024] = qkv[(b*1024+kv)*3072 + 2048 + h*64 + d]
// grid: (16 kv-tiles, nb*16 bh)
__global__ __launch_bounds__(TPB)
void vt_build(const ushort* __restrict__ qkv, ushort* __restrict__ vt)
{
  __shared__ ushort t[64][72];
  const int tid = threadIdx.x;
  const int bh = blockIdx.y, b = bh >> 4, h = bh & 15;
  const int kv0 = blockIdx.x * 64;
#pragma unroll
  for (int it = 0; it < 2; ++it) {
    int idx = (it * TPB + tid) * 8;
    int r = idx >> 6, cc = idx & 63;
    s16x8 v = *(const s16x8*)(qkv + ((long)((b << 10) + kv0 + r)) * 3072 + 2048 + (h << 6) + cc);
#pragma unroll
    for (int j = 0; j < 8; ++j) t[r][cc + j] = (ushort)v[j];
  }
  __syncthreads();
#pragma unroll
  for (int it = 0; it < 2; ++it) {
    int idx = (it * TPB + tid) * 8;
    int dd = idx >> 6, kvo = idx & 63;
    ushort tmp[8];
#pragma unroll
    for (int j = 0; j < 8; ++j) tmp[j] = t[kvo + j][dd];
    *(s16x8*)(vt + ((long)bh * 64 + dd) * 1024 + kv0 + kvo) = *(const s16x8*)tmp;
  }
}

// weight prep ---------------------------------------------------------------
__global__ __launch_bounds__(TPB)
void wt_build(const float* __restrict__ in, ushort* __restrict__ out)
{ // out[n*1024+k] = bf16(in[k*1024+n])   (1024x1024)
  long idx = (long)blockIdx.x * TPB + threadIdx.x;
  int n = (int)(idx >> 10), k = (int)(idx & 1023);
  out[idx] = f2bf(in[((long)k << 10) + n]);
}
__global__ __launch_bounds__(TPB)
void tap_build(const float* __restrict__ w, ushort* __restrict__ out, int f)
{ // out[t][o*1024+i] = bf16(w[(o*1024+i)*f + t])
  long idx = (long)blockIdx.x * TPB + threadIdx.x;
  long oi = idx & 1048575; int t = (int)(idx >> 20);
  out[idx] = f2bf(w[oi * f + t]);
}
__global__ __launch_bounds__(TPB)
void bn_prep(const float* __restrict__ cb, const float* __restrict__ g,
             const float* __restrict__ bb, const float* __restrict__ m,
             const float* __restrict__ v, float* __restrict__ sc, float* __restrict__ sh)
{
  int i = blockIdx.x * TPB + threadIdx.x;
  float s = g[i] * rsqrtf(v[i] + 1e-5f);
  sc[i] = s;
  sh[i] = (cb[i] - m[i]) * s + bb[i];
}
__global__ __launch_bounds__(TPB)
void qkvb_build(const float* __restrict__ bq, const float* __restrict__ bk,
                const float* __restrict__ bv, float* __restrict__ out)
{
  int i = blockIdx.x * TPB + threadIdx.x;
  out[i] = (i < 1024) ? bq[i] : (i < 2048 ? bk[i - 1024] : bv[i - 2048]);
}
__global__ void zero_ws(ushort* z) { z[threadIdx.x] = 0; }

// ---------------------------------------------------------------------------
extern "C" void kernel_launch(void* const* d_in, const int* in_sizes, int n_in,
                              void* d_out, int out_size, void* d_ws, size_t ws_size,
                              hipStream_t stream)
{
  const float* X  = (const float*)d_in[0];
  const float* Wq = (const float*)d_in[1];
  const float* Wk = (const float*)d_in[2];
  const float* Wv = (const float*)d_in[3];
  const float* Wo = (const float*)d_in[4];
  const float* Bq = (const float*)d_in[5];
  const float* Bk = (const float*)d_in[6];
  const float* Bv = (const float*)d_in[7];
  const float* Bo = (const float*)d_in[8];
  const float *CW[3], *CB[3], *BG[3], *BBe[3], *BMu[3], *BVa[3];
  for (int i = 0; i < 3; ++i) {
    CW[i]  = (const float*)d_in[9 + 6 * i];
    CB[i]  = (const float*)d_in[10 + 6 * i];
    BG[i]  = (const float*)d_in[11 + 6 * i];
    BBe[i] = (const float*)d_in[12 + 6 * i];
    BMu[i] = (const float*)d_in[13 + 6 * i];
    BVa[i] = (const float*)d_in[14 + 6 * i];
  }
  const float* L1a = (const float*)d_in[27];
  const float* L2a = (const float*)d_in[28];
  const float* LFa = (const float*)d_in[29];
  const float* L1b = (const float*)d_in[30];
  const float* L2b = (const float*)d_in[31];
  const float* LFb = (const float*)d_in[32];

  // ------ workspace layout ------
  char* p = (char*)d_ws;
  auto carve = [&](size_t bytes) { char* r = p; p += (bytes + 255) & ~(size_t)255; return r; };
  ushort* abuf  = (ushort*)carve(16777216);   // LN out bf16; tierA: also attn-out
  ushort* wqkvt = (ushort*)carve(6291456);
  ushort* wot   = (ushort*)carve(2097152);
  ushort* wtap  = (ushort*)carve(18874368);   // 9 taps [1024,1024] bf16
  float*  qkvb  = (float*) carve(12288);
  float*  bnsc  = (float*) carve(12288);
  float*  bnsh  = (float*) carve(12288);
  ushort* zp    = (ushort*)carve(256);
  char*   ps    = p;                          // shared (phase-aliased) region
  const size_t Pbytes = (size_t)(ps - (char*)d_ws);
  const size_t avail  = ws_size > Pbytes ? ws_size - Pbytes : 0;
  const size_t NEED_A = 100663296;  // qkv 48M + vt 16M + scores(16 heads) 32M
  const size_t NEED_B = 50331648;   // obuf 16M + qkv1 6M + vt1 2M + scores4 8M
  const bool tierA = avail >= NEED_A;
  if (!tierA && avail < NEED_B) return;       // cannot run at all

  float* xbuf = (float*)d_out;                // residual stream lives in d_out

  ushort *qkv, *vt, *scores, *obuf;
  if (tierA) {
    qkv    = (ushort*)ps;
    vt     = (ushort*)(ps + 50331648);
    scores = (ushort*)(ps + 67108864);
    obuf   = abuf;                            // LN1 out dead after QKV GEMM
  } else {
    obuf   = (ushort*)ps;
    qkv    = (ushort*)(ps + 16777216);        // per-batch [1024][3072]
    vt     = (ushort*)(ps + 16777216 + 6291456);
    scores = (ushort*)(ps + 16777216 + 6291456 + 2097152);  // 4 heads
  }

  // per-call weight prep (graph-safe: identical work every call)
  wt_build<<<4096, TPB, 0, stream>>>(Wq, wqkvt);
  wt_build<<<4096, TPB, 0, stream>>>(Wk, wqkvt + 1048576);
  wt_build<<<4096, TPB, 0, stream>>>(Wv, wqkvt + 2097152);
  wt_build<<<4096, TPB, 0, stream>>>(Wo, wot);
  tap_build<<<4096, TPB, 0, stream>>>(CW[0], wtap, 1);
  tap_build<<<3 * 4096, TPB, 0, stream>>>(CW[1], wtap + 1048576, 3);
  tap_build<<<5 * 4096, TPB, 0, stream>>>(CW[2], wtap + 4 * 1048576, 5);
  for (int i = 0; i < 3; ++i)
    bn_prep<<<4, TPB, 0, stream>>>(CB[i], BG[i], BBe[i], BMu[i], BVa[i],
                                   bnsc + i * 1024, bnsh + i * 1024);
  qkvb_build<<<12, TPB, 0, stream>>>(Bq, Bk, Bv, qkvb);
  zero_ws<<<1, 128, 0, stream>>>(zp);

  for (int L = 0; L < 2; ++L) {
    const float* xs = (L == 0) ? X : xbuf;
    // ---- x + MHA(LN1(x)) ----
    ln_rows<true><<<8192, TPB, 0, stream>>>(xs, L1a, L1b, abuf);
    if (tierA) {
      gemm_bt<128, true, false, true, false><<<dim3(64, 24, 1), TPB, 0, stream>>>(
          abuf, 1024, 0, 0, wqkvt, 1024, 0, 0, qkv, 3072, 0, 0, qkvb, nullptr, 1024, 0, zp);
      vt_build<<<dim3(16, 128), TPB, 0, stream>>>(qkv, vt);
      for (int b = 0; b < 8; ++b) {           // 1 batch (16 heads) per chunk
        const ushort* qb = qkv + (long)b * 3145728;
        gemm_bt<128, true, false, false, false><<<dim3(8, 8, 16), TPB, 0, stream>>>(
            qb, 3072, 0, 64, qb + 1024, 3072, 0, 64,
            scores, 1024, 0, 1048576, nullptr, nullptr, 64, 0, zp);
        softmax_rows<<<16384, TPB, 0, stream>>>(scores);
        gemm_bt<64, true, false, false, false><<<dim3(8, 1, 16), TPB, 0, stream>>>(
            scores, 1024, 0, 1048576, vt + (long)b * 1048576, 1024, 0, 65536,
            obuf + (long)b * 1048576, 1024, 0, 64, nullptr, nullptr, 1024, 0, zp);
      }
    } else {
      for (int b = 0; b < 8; ++b) {           // per-batch QKV + 4-head chunks
        gemm_bt<128, true, false, true, false><<<dim3(8, 24, 1), TPB, 0, stream>>>(
            abuf + (long)b * 1048576, 1024, 0, 0, wqkvt, 1024, 0, 0,
            qkv, 3072, 0, 0, qkvb, nullptr, 1024, 0, zp);
        vt_build<<<dim3(16, 16), TPB, 0, stream>>>(qkv, vt);
        for (int hc = 0; hc < 4; ++hc) {
          const ushort* qh = qkv + hc * 256;
          gemm_bt<128, true, false, false, false><<<dim3(8, 8, 4), TPB, 0, stream>>>(
              qh, 3072, 0, 64, qh + 1024, 3072, 0, 64,
              scores, 1024, 0, 1048576, nullptr, nullptr, 64, 0, zp);
          softmax_rows<<<4096, TPB, 0, stream>>>(scores);
          gemm_bt<64, true, false, false, false><<<dim3(8, 1, 4), TPB, 0, stream>>>(
              scores, 1024, 0, 1048576, vt + hc * 262144, 1024, 0, 65536,
              obuf + (long)b * 1048576 + hc * 256, 1024, 0, 64,
              nullptr, nullptr, 1024, 0, zp);
        }
      }
    }
    gemm_bt<128, false, false, true, true><<<dim3(64, 8, 1), TPB, 0, stream>>>(
        obuf, 1024, 0, 0, wot, 1024, 0, 0, xbuf, 1024, 0, 0, Bo, xs, 1024, 0, zp);
    // ---- x + FFN(LN2(x)): one fused dispatch ----
    ln_rows<true><<<8192, TPB, 0, stream>>>(xbuf, L2a, L2b, abuf);
    conv_fused<<<dim3(64, 8), TPB, 0, stream>>>(abuf, wtap, xbuf, bnsc, bnsh, zp);
  }
  ln_rows<false><<<8192, TPB, 0, stream>>>(xbuf, LFa, LFb, d_out);
}

// Round 4
// 1076.404 us; speedup vs baseline: 1.8557x; 1.4852x over previous
//
#include <hip/hip_runtime.h>

#define TPB 256

typedef __attribute__((ext_vector_type(4))) float f32x4;
typedef __attribute__((ext_vector_type(8))) short s16x8;

__device__ __forceinline__ ushort f2bf(float f) {
  unsigned x = __float_as_uint(f);
  return (ushort)((x + 0x7fffu + ((x >> 16) & 1u)) >> 16);
}
__device__ __forceinline__ float b2f(ushort u) {
  return __uint_as_float(((unsigned)u) << 16);
}
__device__ __forceinline__ void gload_lds16(const ushort* g, ushort* l) {
  __builtin_amdgcn_global_load_lds(
      (const __attribute__((address_space(1))) void*)g,
      (__attribute__((address_space(3))) void*)l, 16, 0, 0);
}

__device__ __forceinline__ float blk_sum(float v, float* red, int tid) {
#pragma unroll
  for (int o = 32; o; o >>= 1) v += __shfl_xor(v, o);
  if ((tid & 63) == 0) red[tid >> 6] = v;
  __syncthreads();
  float r = red[0] + red[1] + red[2] + red[3];
  __syncthreads();
  return r;
}

// ---------------------------------------------------------------------------
// GEMM: C[M,N] = A[M,K](bf16) @ Bt[N,K]^T(bf16)  (+bias, +residual)
// 128x128 tile, BK=32, 4 waves 2x2, 16x16x32 bf16 MFMA.
// ---------------------------------------------------------------------------
template<bool C_BF16, bool HAS_BIAS, bool HAS_RES>
__global__ __launch_bounds__(TPB, 2)
void gemm_bt(const ushort* __restrict__ A, int lda,
             const ushort* __restrict__ B, int ldb,
             void* __restrict__ Cp, int ldc,
             const float* __restrict__ bias, const float* __restrict__ Res, int K)
{
  constexpr int BM = 128, BK = 32;
  __shared__ ushort lA[BM * BK];
  __shared__ ushort lB[128 * BK];
  const int tid = threadIdx.x;
  const int rowBase = blockIdx.x * BM;
  const int colBase = blockIdx.y * 128;
  const int w = tid >> 6, lane = tid & 63;
  const int wr = w >> 1, wc = w & 1;
  const int lr = lane & 15, lk = (lane >> 4) * 8;

  f32x4 acc[4][4] = {};

  for (int k0 = 0; k0 < K; k0 += BK) {
#pragma unroll
    for (int i = 0; i < 2; ++i) {
      int idx = i * TPB + tid;
      int r = idx >> 2, kk = (idx & 3) * 8;
      gload_lds16(A + (long)(rowBase + r) * lda + k0 + kk, &lA[idx * 8]);
    }
#pragma unroll
    for (int i = 0; i < 2; ++i) {
      int idx = i * TPB + tid;
      int r = idx >> 2, kk = (idx & 3) * 8;
      gload_lds16(B + (long)(colBase + r) * ldb + k0 + kk, &lB[idx * 8]);
    }
    __syncthreads();
    s16x8 af[4], bfr[4];
#pragma unroll
    for (int m = 0; m < 4; ++m)
      af[m] = *(const s16x8*)&lA[(wr * 64 + m * 16 + lr) * BK + lk];
#pragma unroll
    for (int n = 0; n < 4; ++n)
      bfr[n] = *(const s16x8*)&lB[(wc * 64 + n * 16 + lr) * BK + lk];
#pragma unroll
    for (int m = 0; m < 4; ++m)
#pragma unroll
      for (int n = 0; n < 4; ++n)
        acc[m][n] = __builtin_amdgcn_mfma_f32_16x16x32_bf16(af[m], bfr[n], acc[m][n], 0, 0, 0);
    __syncthreads();
  }

  const int crow0 = rowBase + wr * 64 + (lane >> 4) * 4;
#pragma unroll
  for (int m = 0; m < 4; ++m) {
#pragma unroll
    for (int n = 0; n < 4; ++n) {
      const int ccol = colBase + wc * 64 + n * 16 + lr;
      const float bv = HAS_BIAS ? bias[ccol] : 0.f;
#pragma unroll
      for (int j = 0; j < 4; ++j) {
        const long off = (long)(crow0 + m * 16 + j) * ldc + ccol;
        float v = acc[m][n][j] + bv;
        if (HAS_RES) v += Res[off];
        if (C_BF16) ((ushort*)Cp)[off] = f2bf(v);
        else        ((float*)Cp)[off] = v;
      }
    }
  }
}

// ---------------------------------------------------------------------------
// Fused conv FFN: x += mean_br relu(bn_br(conv_br(A))), one dispatch/layer.
// ---------------------------------------------------------------------------
__global__ __launch_bounds__(TPB, 2)
void conv_fused(const ushort* __restrict__ A, const ushort* __restrict__ W,
                float* __restrict__ x, const float* __restrict__ sc,
                const float* __restrict__ sh, const ushort* __restrict__ zp)
{
  constexpr int BM = 128, BK = 32;
  __shared__ ushort lA[BM * BK];
  __shared__ ushort lB[128 * BK];
  const int tid = threadIdx.x;
  const int rowBase = blockIdx.x * BM;
  const int colBase = blockIdx.y * 128;
  const int w = tid >> 6, lane = tid & 63;
  const int wr = w >> 1, wc = w & 1;
  const int lr = lane & 15, lk = (lane >> 4) * 8;

  f32x4 acc[4][4] = {};
  f32x4 res[4][4] = {};

  for (int s = 0; s < 9; ++s) {
    const int shift = (s == 0) ? 0 : ((s <= 3) ? s - 2 : s - 6);
    const ushort* Wseg = W + (long)s * 1048576;
    for (int k0 = 0; k0 < 1024; k0 += BK) {
#pragma unroll
      for (int i = 0; i < 2; ++i) {
        int idx = i * TPB + tid;
        int r = idx >> 2, kk = (idx & 3) * 8;
        int gr = rowBase + r;
        int sr = (gr & 1023) + shift;
        const ushort* src = ((unsigned)sr < 1024u)
            ? (A + (long)((gr & ~1023) + sr) * 1024 + k0 + kk) : zp;
        gload_lds16(src, &lA[idx * 8]);
      }
#pragma unroll
      for (int i = 0; i < 2; ++i) {
        int idx = i * TPB + tid;
        int r = idx >> 2, kk = (idx & 3) * 8;
        gload_lds16(Wseg + (long)(colBase + r) * 1024 + k0 + kk, &lB[idx * 8]);
      }
      __syncthreads();
      s16x8 af[4], bfr[4];
#pragma unroll
      for (int m = 0; m < 4; ++m)
        af[m] = *(const s16x8*)&lA[(wr * 64 + m * 16 + lr) * BK + lk];
#pragma unroll
      for (int n = 0; n < 4; ++n)
        bfr[n] = *(const s16x8*)&lB[(wc * 64 + n * 16 + lr) * BK + lk];
#pragma unroll
      for (int m = 0; m < 4; ++m)
#pragma unroll
        for (int n = 0; n < 4; ++n)
          acc[m][n] = __builtin_amdgcn_mfma_f32_16x16x32_bf16(af[m], bfr[n], acc[m][n], 0, 0, 0);
      __syncthreads();
    }
    if (s == 0 || s == 3 || s == 8) {
      const int br = (s == 0) ? 0 : (s == 3 ? 1 : 2);
#pragma unroll
      for (int n = 0; n < 4; ++n) {
        const int col = colBase + wc * 64 + n * 16 + lr;
        const float scv = sc[br * 1024 + col];
        const float shv = sh[br * 1024 + col];
#pragma unroll
        for (int m = 0; m < 4; ++m)
#pragma unroll
          for (int j = 0; j < 4; ++j) {
            res[m][n][j] += fmaxf(acc[m][n][j] * scv + shv, 0.f);
            acc[m][n][j] = 0.f;
          }
      }
    }
  }

  const int crow0 = rowBase + wr * 64 + (lane >> 4) * 4;
#pragma unroll
  for (int m = 0; m < 4; ++m)
#pragma unroll
    for (int n = 0; n < 4; ++n) {
      const int col = colBase + wc * 64 + n * 16 + lr;
#pragma unroll
      for (int j = 0; j < 4; ++j) {
        const long off = (long)(crow0 + m * 16 + j) * 1024 + col;
        x[off] += res[m][n][j] * (1.f / 3.f);
      }
    }
}

// ---------------------------------------------------------------------------
// Flash attention: grid (8 q-tiles, 128 bh), 4 waves x 32 q-rows, KV tiles 64.
// S = softmax(QK^T/8) online; P restaged via per-wave LDS tile for PV A-frags.
// ---------------------------------------------------------------------------
__global__ __launch_bounds__(TPB)
void flash_attn(const ushort* __restrict__ qkv, const ushort* __restrict__ vt,
                ushort* __restrict__ obuf)
{
  __shared__ ushort lK[64 * 64];    // [kv][d]
  __shared__ ushort lVt[64 * 64];   // [d][kv]
  __shared__ ushort lP[4 * 32 * 64]; // per-wave [q][kv]
  const int tid = threadIdx.x;
  const int w = tid >> 6, lane = tid & 63;
  const int g = lane >> 4, c = lane & 15;
  const int bh = blockIdx.y, b = bh >> 4, h = bh & 15;
  const int qw = blockIdx.x * 128 + w * 32;
  const float c8 = 0.18033688f;     // log2(e)/8  -> softmax(s/8)

  // Q fragments, loaded once: A[row=q(lane&15), k=d((lane>>4)*8+e)]
  s16x8 qfr[2][2];
#pragma unroll
  for (int qf = 0; qf < 2; ++qf)
#pragma unroll
    for (int ds = 0; ds < 2; ++ds)
      qfr[qf][ds] = *(const s16x8*)(qkv
          + (long)((b << 10) + qw + qf * 16 + c) * 3072 + (h << 6) + ds * 32 + g * 8);

  f32x4 acc_o[2][4] = {};
  float m[2][4], l[2][4];
#pragma unroll
  for (int qf = 0; qf < 2; ++qf)
#pragma unroll
    for (int j = 0; j < 4; ++j) { m[qf][j] = -3.0e38f; l[qf][j] = 0.f; }

  ushort* lPw = &lP[w * 2048];

  for (int t = 0; t < 16; ++t) {
    const int kv0 = t * 64;
#pragma unroll
    for (int i = 0; i < 2; ++i) {   // K tile: [kv][64]
      int idx = i * TPB + tid;
      int r = idx >> 3, dc = (idx & 7) * 8;
      gload_lds16(qkv + (long)((b << 10) + kv0 + r) * 3072 + 1024 + (h << 6) + dc,
                  &lK[idx * 8]);
    }
#pragma unroll
    for (int i = 0; i < 2; ++i) {   // V^T tile: [d][64]
      int idx = i * TPB + tid;
      int r = idx >> 3, dc = (idx & 7) * 8;
      gload_lds16(vt + (long)((bh << 6) + r) * 1024 + kv0 + dc, &lVt[idx * 8]);
    }
    __syncthreads();

    // S = Q @ K^T : C[row=q, col=kv]
    f32x4 s[2][4] = {};
#pragma unroll
    for (int ds = 0; ds < 2; ++ds) {
      s16x8 bk[4];
#pragma unroll
      for (int kf = 0; kf < 4; ++kf)
        bk[kf] = *(const s16x8*)&lK[(kf * 16 + c) * 64 + ds * 32 + g * 8];
#pragma unroll
      for (int qf = 0; qf < 2; ++qf)
#pragma unroll
        for (int kf = 0; kf < 4; ++kf)
          s[qf][kf] = __builtin_amdgcn_mfma_f32_16x16x32_bf16(qfr[qf][ds], bk[kf], s[qf][kf], 0, 0, 0);
    }

    // online softmax; row q = qf*16 + g*4 + j spans the 16 c-lanes
#pragma unroll
    for (int qf = 0; qf < 2; ++qf)
#pragma unroll
      for (int j = 0; j < 4; ++j) {
        float tm = fmaxf(fmaxf(s[qf][0][j], s[qf][1][j]), fmaxf(s[qf][2][j], s[qf][3][j]));
        tm = fmaxf(tm, __shfl_xor(tm, 1));
        tm = fmaxf(tm, __shfl_xor(tm, 2));
        tm = fmaxf(tm, __shfl_xor(tm, 4));
        tm = fmaxf(tm, __shfl_xor(tm, 8));
        float mn = fmaxf(m[qf][j], tm);
        float scale = exp2f((m[qf][j] - mn) * c8);
        m[qf][j] = mn;
        l[qf][j] *= scale;
#pragma unroll
        for (int df = 0; df < 4; ++df) acc_o[qf][df][j] *= scale;
        float ps = 0.f;
#pragma unroll
        for (int kf = 0; kf < 4; ++kf) {
          float pv = exp2f((s[qf][kf][j] - mn) * c8);
          ps += pv;
          lPw[(qf * 16 + g * 4 + j) * 64 + kf * 16 + c] = f2bf(pv);
        }
        l[qf][j] += ps;   // lane-partial over kv ≡ c (mod 16); reduced at end
      }

    // O += P @ V : A[row=q, k=kv] from lPw, B[col=d, k=kv] from lVt
#pragma unroll
    for (int kvb = 0; kvb < 2; ++kvb) {
      s16x8 pA[2], vB[4];
#pragma unroll
      for (int qf = 0; qf < 2; ++qf)
        pA[qf] = *(const s16x8*)&lPw[(qf * 16 + c) * 64 + kvb * 32 + g * 8];
#pragma unroll
      for (int df = 0; df < 4; ++df)
        vB[df] = *(const s16x8*)&lVt[(df * 16 + c) * 64 + kvb * 32 + g * 8];
#pragma unroll
      for (int qf = 0; qf < 2; ++qf)
#pragma unroll
        for (int df = 0; df < 4; ++df)
          acc_o[qf][df] = __builtin_amdgcn_mfma_f32_16x16x32_bf16(pA[qf], vB[df], acc_o[qf][df], 0, 0, 0);
    }
    __syncthreads();
  }

#pragma unroll
  for (int qf = 0; qf < 2; ++qf)
#pragma unroll
    for (int j = 0; j < 4; ++j) {
      float lv = l[qf][j];
      lv += __shfl_xor(lv, 1);
      lv += __shfl_xor(lv, 2);
      lv += __shfl_xor(lv, 4);
      lv += __shfl_xor(lv, 8);
      float inv = 1.f / lv;
#pragma unroll
      for (int df = 0; df < 4; ++df)
        obuf[(long)((b << 10) + qw + qf * 16 + g * 4 + j) * 1024 + (h << 6) + df * 16 + c]
            = f2bf(acc_o[qf][df][j] * inv);
    }
}

// LayerNorm (torch variant: unbiased std, eps added to std). One block per row.
template<bool OBF>
__global__ __launch_bounds__(TPB)
void ln_rows(const float* __restrict__ X, const float* __restrict__ ga,
             const float* __restrict__ gb, void* __restrict__ out)
{
  __shared__ float red[4];
  const int tid = threadIdx.x;
  const long base = (long)blockIdx.x * 1024;
  f32x4 v = *(const f32x4*)&X[base + tid * 4];
  float mean = blk_sum(v[0] + v[1] + v[2] + v[3], red, tid) * (1.f / 1024.f);
  f32x4 d = v - mean;
  float qs = blk_sum(d[0]*d[0] + d[1]*d[1] + d[2]*d[2] + d[3]*d[3], red, tid);
  float inv = 1.f / (sqrtf(qs * (1.f / 1023.f)) + 1e-6f);
  f32x4 a4 = *(const f32x4*)&ga[tid * 4];
  f32x4 b4 = *(const f32x4*)&gb[tid * 4];
  f32x4 r = a4 * (d * inv) + b4;
  if (OBF) {
    ushort4 o4 = { f2bf(r[0]), f2bf(r[1]), f2bf(r[2]), f2bf(r[3]) };
    *(ushort4*)((ushort*)out + base + tid * 4) = o4;
  } else {
    *(f32x4*)((float*)out + base + tid * 4) = r;
  }
}

// vt[b*16+h][d=64][kv=1024] = qkv[(b*1024+kv)*3072 + 2048 + h*64 + d]
__global__ __launch_bounds__(TPB)
void vt_build(const ushort* __restrict__ qkv, ushort* __restrict__ vt)
{
  __shared__ ushort t[64][72];
  const int tid = threadIdx.x;
  const int bh = blockIdx.y, b = bh >> 4, h = bh & 15;
  const int kv0 = blockIdx.x * 64;
#pragma unroll
  for (int it = 0; it < 2; ++it) {
    int idx = (it * TPB + tid) * 8;
    int r = idx >> 6, cc = idx & 63;
    s16x8 v = *(const s16x8*)(qkv + ((long)((b << 10) + kv0 + r)) * 3072 + 2048 + (h << 6) + cc);
#pragma unroll
    for (int j = 0; j < 8; ++j) t[r][cc + j] = (ushort)v[j];
  }
  __syncthreads();
#pragma unroll
  for (int it = 0; it < 2; ++it) {
    int idx = (it * TPB + tid) * 8;
    int dd = idx >> 6, kvo = idx & 63;
    ushort tmp[8];
#pragma unroll
    for (int j = 0; j < 8; ++j) tmp[j] = t[kvo + j][dd];
    *(s16x8*)(vt + ((long)bh * 64 + dd) * 1024 + kv0 + kvo) = *(const s16x8*)tmp;
  }
}

// weight prep ---------------------------------------------------------------
// out[n*1024+k] = bf16(in[k*1024+n]); LDS-tiled transpose, both sides coalesced
__global__ __launch_bounds__(TPB)
void wt_build(const float* __restrict__ in, ushort* __restrict__ out)
{
  __shared__ float t[64][65];
  const int tid = threadIdx.x;
  const int k0 = blockIdx.x * 64, n0 = blockIdx.y * 64;
#pragma unroll
  for (int it = 0; it < 4; ++it) {
    int idx = it * TPB + tid;
    int r = idx >> 4, c4 = (idx & 15) * 4;
    f32x4 v = *(const f32x4*)&in[(long)(k0 + r) * 1024 + n0 + c4];
    t[r][c4] = v[0]; t[r][c4 + 1] = v[1]; t[r][c4 + 2] = v[2]; t[r][c4 + 3] = v[3];
  }
  __syncthreads();
#pragma unroll
  for (int it = 0; it < 4; ++it) {
    int idx = it * TPB + tid;
    int nr = idx >> 4, k4 = (idx & 15) * 4;
    ushort4 o = { f2bf(t[k4][nr]), f2bf(t[k4 + 1][nr]),
                  f2bf(t[k4 + 2][nr]), f2bf(t[k4 + 3][nr]) };
    *(ushort4*)&out[(long)(n0 + nr) * 1024 + k0 + k4] = o;
  }
}
__global__ __launch_bounds__(TPB)
void tap_build(const float* __restrict__ w, ushort* __restrict__ out, int f)
{ // out[t][o*1024+i] = bf16(w[(o*1024+i)*f + t])
  long idx = (long)blockIdx.x * TPB + threadIdx.x;
  long oi = idx & 1048575; int t = (int)(idx >> 20);
  out[idx] = f2bf(w[oi * f + t]);
}
__global__ __launch_bounds__(TPB)
void bn_prep(const float* __restrict__ cb, const float* __restrict__ g,
             const float* __restrict__ bb, const float* __restrict__ m,
             const float* __restrict__ v, float* __restrict__ sc, float* __restrict__ sh)
{
  int i = blockIdx.x * TPB + threadIdx.x;
  float s = g[i] * rsqrtf(v[i] + 1e-5f);
  sc[i] = s;
  sh[i] = (cb[i] - m[i]) * s + bb[i];
}
__global__ __launch_bounds__(TPB)
void qkvb_build(const float* __restrict__ bq, const float* __restrict__ bk,
                const float* __restrict__ bv, float* __restrict__ out)
{
  int i = blockIdx.x * TPB + threadIdx.x;
  out[i] = (i < 1024) ? bq[i] : (i < 2048 ? bk[i - 1024] : bv[i - 2048]);
}
__global__ void zero_ws(ushort* z) { z[threadIdx.x] = 0; }

// ---------------------------------------------------------------------------
extern "C" void kernel_launch(void* const* d_in, const int* in_sizes, int n_in,
                              void* d_out, int out_size, void* d_ws, size_t ws_size,
                              hipStream_t stream)
{
  const float* X  = (const float*)d_in[0];
  const float* Wq = (const float*)d_in[1];
  const float* Wk = (const float*)d_in[2];
  const float* Wv = (const float*)d_in[3];
  const float* Wo = (const float*)d_in[4];
  const float* Bq = (const float*)d_in[5];
  const float* Bk = (const float*)d_in[6];
  const float* Bv = (const float*)d_in[7];
  const float* Bo = (const float*)d_in[8];
  const float *CW[3], *CB[3], *BG[3], *BBe[3], *BMu[3], *BVa[3];
  for (int i = 0; i < 3; ++i) {
    CW[i]  = (const float*)d_in[9 + 6 * i];
    CB[i]  = (const float*)d_in[10 + 6 * i];
    BG[i]  = (const float*)d_in[11 + 6 * i];
    BBe[i] = (const float*)d_in[12 + 6 * i];
    BMu[i] = (const float*)d_in[13 + 6 * i];
    BVa[i] = (const float*)d_in[14 + 6 * i];
  }
  const float* L1a = (const float*)d_in[27];
  const float* L2a = (const float*)d_in[28];
  const float* LFa = (const float*)d_in[29];
  const float* L1b = (const float*)d_in[30];
  const float* L2b = (const float*)d_in[31];
  const float* LFb = (const float*)d_in[32];

  char* p = (char*)d_ws;
  auto carve = [&](size_t bytes) { char* r = p; p += (bytes + 255) & ~(size_t)255; return r; };
  ushort* abuf  = (ushort*)carve(16777216);   // LN out bf16 [8192][1024]
  ushort* wqkvt = (ushort*)carve(6291456);
  ushort* wot   = (ushort*)carve(2097152);
  ushort* wtap  = (ushort*)carve(18874368);   // 9 taps [1024,1024] bf16
  ushort* qkv   = (ushort*)carve(50331648);   // bf16 [8192][3072]
  ushort* vt    = (ushort*)carve(16777216);   // V^T bf16 [128][64][1024]
  ushort* obuf  = (ushort*)carve(16777216);   // attn out bf16 [8192][1024]
  float*  qkvb  = (float*) carve(12288);
  float*  bnsc  = (float*) carve(12288);
  float*  bnsh  = (float*) carve(12288);
  ushort* zp    = (ushort*)carve(256);
  if ((size_t)(p - (char*)d_ws) > ws_size) return;  // ~123 MB; known to fit

  float* xbuf = (float*)d_out;                // residual stream lives in d_out

  // per-call weight prep (graph-safe: identical work every call)
  wt_build<<<dim3(16, 16), TPB, 0, stream>>>(Wq, wqkvt);
  wt_build<<<dim3(16, 16), TPB, 0, stream>>>(Wk, wqkvt + 1048576);
  wt_build<<<dim3(16, 16), TPB, 0, stream>>>(Wv, wqkvt + 2097152);
  wt_build<<<dim3(16, 16), TPB, 0, stream>>>(Wo, wot);
  tap_build<<<4096, TPB, 0, stream>>>(CW[0], wtap, 1);
  tap_build<<<3 * 4096, TPB, 0, stream>>>(CW[1], wtap + 1048576, 3);
  tap_build<<<5 * 4096, TPB, 0, stream>>>(CW[2], wtap + 4 * 1048576, 5);
  for (int i = 0; i < 3; ++i)
    bn_prep<<<4, TPB, 0, stream>>>(CB[i], BG[i], BBe[i], BMu[i], BVa[i],
                                   bnsc + i * 1024, bnsh + i * 1024);
  qkvb_build<<<12, TPB, 0, stream>>>(Bq, Bk, Bv, qkvb);
  zero_ws<<<1, 128, 0, stream>>>(zp);

  for (int L = 0; L < 2; ++L) {
    const float* xs = (L == 0) ? X : xbuf;
    // ---- x + MHA(LN1(x)) ----
    ln_rows<true><<<8192, TPB, 0, stream>>>(xs, L1a, L1b, abuf);
    gemm_bt<true, true, false><<<dim3(64, 24), TPB, 0, stream>>>(
        abuf, 1024, wqkvt, 1024, qkv, 3072, qkvb, nullptr, 1024);
    vt_build<<<dim3(16, 128), TPB, 0, stream>>>(qkv, vt);
    flash_attn<<<dim3(8, 128), TPB, 0, stream>>>(qkv, vt, obuf);
    gemm_bt<false, true, true><<<dim3(64, 8), TPB, 0, stream>>>(
        obuf, 1024, wot, 1024, xbuf, 1024, Bo, xs, 1024);
    // ---- x + FFN(LN2(x)): one fused dispatch ----
    ln_rows<true><<<8192, TPB, 0, stream>>>(xbuf, L2a, L2b, abuf);
    conv_fused<<<dim3(64, 8), TPB, 0, stream>>>(abuf, wtap, xbuf, bnsc, bnsh, zp);
  }
  ln_rows<false><<<8192, TPB, 0, stream>>>(xbuf, LFa, LFb, d_out);
}

// Round 6
// 1024.437 us; speedup vs baseline: 1.9498x; 1.0507x over previous
//
#include <hip/hip_runtime.h>

#define TPB 256

typedef __attribute__((ext_vector_type(4))) float f32x4;
typedef __attribute__((ext_vector_type(8))) short s16x8;

__device__ __forceinline__ ushort f2bf(float f) {
  unsigned x = __float_as_uint(f);
  return (ushort)((x + 0x7fffu + ((x >> 16) & 1u)) >> 16);
}
__device__ __forceinline__ float b2f(ushort u) {
  return __uint_as_float(((unsigned)u) << 16);
}
__device__ __forceinline__ void gload_lds16(const ushort* g, ushort* l) {
  __builtin_amdgcn_global_load_lds(
      (const __attribute__((address_space(1))) void*)g,
      (__attribute__((address_space(3))) void*)l, 16, 0, 0);
}

__device__ __forceinline__ float blk_sum(float v, float* red, int tid) {
#pragma unroll
  for (int o = 32; o; o >>= 1) v += __shfl_xor(v, o);
  if ((tid & 63) == 0) red[tid >> 6] = v;
  __syncthreads();
  float r = red[0] + red[1] + red[2] + red[3];
  __syncthreads();
  return r;
}

// ---------------------------------------------------------------------------
// GEMM: C[M,N] = A[M,K](bf16) @ Bt[N,K]^T(bf16)  (+bias, +residual)
// 128x128 tile, BK=32, 4 waves 2x2, 16x16x32 bf16 MFMA.
// ---------------------------------------------------------------------------
template<bool C_BF16, bool HAS_BIAS, bool HAS_RES>
__global__ __launch_bounds__(TPB, 2)
void gemm_bt(const ushort* __restrict__ A, int lda,
             const ushort* __restrict__ B, int ldb,
             void* __restrict__ Cp, int ldc,
             const float* __restrict__ bias, const float* __restrict__ Res, int K)
{
  constexpr int BM = 128, BK = 32;
  __shared__ ushort lA[BM * BK];
  __shared__ ushort lB[128 * BK];
  const int tid = threadIdx.x;
  const int rowBase = blockIdx.x * BM;
  const int colBase = blockIdx.y * 128;
  const int w = tid >> 6, lane = tid & 63;
  const int wr = w >> 1, wc = w & 1;
  const int lr = lane & 15, lk = (lane >> 4) * 8;

  f32x4 acc[4][4] = {};

  for (int k0 = 0; k0 < K; k0 += BK) {
#pragma unroll
    for (int i = 0; i < 2; ++i) {
      int idx = i * TPB + tid;
      int r = idx >> 2, kk = (idx & 3) * 8;
      gload_lds16(A + (long)(rowBase + r) * lda + k0 + kk, &lA[idx * 8]);
    }
#pragma unroll
    for (int i = 0; i < 2; ++i) {
      int idx = i * TPB + tid;
      int r = idx >> 2, kk = (idx & 3) * 8;
      gload_lds16(B + (long)(colBase + r) * ldb + k0 + kk, &lB[idx * 8]);
    }
    __syncthreads();
    s16x8 af[4], bfr[4];
#pragma unroll
    for (int m = 0; m < 4; ++m)
      af[m] = *(const s16x8*)&lA[(wr * 64 + m * 16 + lr) * BK + lk];
#pragma unroll
    for (int n = 0; n < 4; ++n)
      bfr[n] = *(const s16x8*)&lB[(wc * 64 + n * 16 + lr) * BK + lk];
#pragma unroll
    for (int m = 0; m < 4; ++m)
#pragma unroll
      for (int n = 0; n < 4; ++n)
        acc[m][n] = __builtin_amdgcn_mfma_f32_16x16x32_bf16(af[m], bfr[n], acc[m][n], 0, 0, 0);
    __syncthreads();
  }

  const int crow0 = rowBase + wr * 64 + (lane >> 4) * 4;
#pragma unroll
  for (int m = 0; m < 4; ++m) {
#pragma unroll
    for (int n = 0; n < 4; ++n) {
      const int ccol = colBase + wc * 64 + n * 16 + lr;
      const float bv = HAS_BIAS ? bias[ccol] : 0.f;
#pragma unroll
      for (int j = 0; j < 4; ++j) {
        const long off = (long)(crow0 + m * 16 + j) * ldc + ccol;
        float v = acc[m][n][j] + bv;
        if (HAS_RES) v += Res[off];
        if (C_BF16) ((ushort*)Cp)[off] = f2bf(v);
        else        ((float*)Cp)[off] = v;
      }
    }
  }
}

// ---------------------------------------------------------------------------
// Fused conv FFN v2: x += mean_br relu(bn_br(conv_br(A))); one dispatch/layer.
// BM=256 x BN=128, BK=64, 8 waves (4Mx2N, wave-tile 64x64), grid 256 = 1/CU.
// Triple-buffered LDS (144KB dynamic), depth-2 prefetch with counted vmcnt(6),
// ONE barrier per K-step (no intra-step barriers: stage writes only buf t+2).
// LDS slot-XOR swizzle (slot ^= row&7, 16B slots) on BOTH stage-source and
// ds_read so ds_read_b128 is ~2-way instead of 32-way bank-conflicted.
// 144 K-steps = 9 segments x 16; branch folds at t=15/63/143 (register-only).
// ---------------------------------------------------------------------------
__global__ __launch_bounds__(512, 2)
void conv_fused2(const ushort* __restrict__ A, const ushort* __restrict__ W9,
                 float* __restrict__ x, const float* __restrict__ sc,
                 const float* __restrict__ sh, const ushort* __restrict__ zp)
{
  extern __shared__ ushort smem[];      // [3][256*64] A + [3][128*64] B
  ushort* lA = smem;                    // 3 * 16384 ushorts
  ushort* lB = smem + 49152;            // 3 * 8192 ushorts
  const int tid = threadIdx.x;
  const int rowBase = blockIdx.x * 256;
  const int colBase = blockIdx.y * 128;
  const int w = tid >> 6, lane = tid & 63;
  const int wrm = w >> 1, wcn = w & 1;  // 4Mx2N wave grid
  const int lr = lane & 15, kg = lane >> 4;

  f32x4 acc[4][4] = {};
  f32x4 res[4][4] = {};

  auto stage = [&](int t, int buf) {
    const int s = t >> 4;                                   // segment 0..8
    const int k0 = (t & 15) * 64;
    const int shift = (s == 0) ? 0 : ((s <= 3) ? s - 2 : s - 6);
    const ushort* Wseg = W9 + (long)s * 1048576 + k0;
    const ushort* Ak = A + k0;
    ushort* dA = lA + buf * 16384;
    ushort* dB = lB + buf * 8192;
#pragma unroll
    for (int i = 0; i < 4; ++i) {       // A: 256 rows x 8 slots, 4 issues
      int li = i * 512 + tid;
      int r = li >> 3, sl = li & 7;
      int gsl = sl ^ (r & 7);           // inverse-swizzled global slot
      int gr = rowBase + r;
      int sr = (gr & 1023) + shift;
      const ushort* src = ((unsigned)sr < 1024u)
          ? (Ak + (long)((gr & ~1023) + sr) * 1024 + gsl * 8) : zp;
      gload_lds16(src, dA + li * 8);
    }
#pragma unroll
    for (int i = 0; i < 2; ++i) {       // B: 128 rows x 8 slots, 2 issues
      int li = i * 512 + tid;
      int r = li >> 3, sl = li & 7;
      int gsl = sl ^ (r & 7);
      gload_lds16(Wseg + (long)(colBase + r) * 1024 + gsl * 8, dB + li * 8);
    }
  };

  // prologue: fill buffers 0,1; wait for buffer 0 (6 of 12 loads drained)
  stage(0, 0);
  stage(1, 1);
  __builtin_amdgcn_sched_barrier(0);
  asm volatile("s_waitcnt vmcnt(6)" ::: "memory");
  __builtin_amdgcn_sched_barrier(0);
  __syncthreads();

#pragma unroll 3
  for (int t = 0; t < 144; ++t) {
    const int cur = t % 3;
    if (t + 2 < 144) stage(t + 2, (t + 2) % 3);

    const ushort* bA = lA + cur * 16384;
    const ushort* bB = lB + cur * 8192;
#pragma unroll
    for (int ks = 0; ks < 2; ++ks) {    // two K=32 halves of BK=64
      s16x8 af[4], bfr[4];
#pragma unroll
      for (int mf = 0; mf < 4; ++mf) {
        int r = wrm * 64 + mf * 16 + lr;
        int sl = (ks * 4 + kg) ^ (r & 7);
        af[mf] = *(const s16x8*)&bA[r * 64 + sl * 8];
      }
#pragma unroll
      for (int nf = 0; nf < 4; ++nf) {
        int r = wcn * 64 + nf * 16 + lr;
        int sl = (ks * 4 + kg) ^ (r & 7);
        bfr[nf] = *(const s16x8*)&bB[r * 64 + sl * 8];
      }
#pragma unroll
      for (int mf = 0; mf < 4; ++mf)
#pragma unroll
        for (int nf = 0; nf < 4; ++nf)
          acc[mf][nf] = __builtin_amdgcn_mfma_f32_16x16x32_bf16(af[mf], bfr[nf], acc[mf][nf], 0, 0, 0);
    }

    if (t == 15 || t == 63 || t == 143) {     // branch boundary fold
      const int br = (t == 15) ? 0 : (t == 63 ? 1 : 2);
#pragma unroll
      for (int nf = 0; nf < 4; ++nf) {
        const int col = colBase + wcn * 64 + nf * 16 + lr;
        const float scv = sc[br * 1024 + col];
        const float shv = sh[br * 1024 + col];
#pragma unroll
        for (int mf = 0; mf < 4; ++mf)
#pragma unroll
          for (int j = 0; j < 4; ++j) {
            res[mf][nf][j] += fmaxf(acc[mf][nf][j] * scv + shv, 0.f);
            acc[mf][nf][j] = 0.f;
          }
      }
    }

    // drain: stage(t+1) must be in LDS before next step (stage(t+2) stays in flight)
    __builtin_amdgcn_sched_barrier(0);
    if (t + 2 < 144)      asm volatile("s_waitcnt vmcnt(6)" ::: "memory");
    else if (t + 1 < 144) asm volatile("s_waitcnt vmcnt(0)" ::: "memory");
    __builtin_amdgcn_sched_barrier(0);
    __syncthreads();
  }

  const int crow0 = rowBase + wrm * 64 + kg * 4;
#pragma unroll
  for (int mf = 0; mf < 4; ++mf)
#pragma unroll
    for (int nf = 0; nf < 4; ++nf) {
      const int col = colBase + wcn * 64 + nf * 16 + lr;
#pragma unroll
      for (int j = 0; j < 4; ++j) {
        const long off = (long)(crow0 + mf * 16 + j) * 1024 + col;
        x[off] += res[mf][nf][j] * (1.f / 3.f);
      }
    }
}

// ---------------------------------------------------------------------------
// Flash attention: grid (8 q-tiles, 128 bh), 4 waves x 32 q-rows, KV tiles 64.
// ---------------------------------------------------------------------------
__global__ __launch_bounds__(TPB)
void flash_attn(const ushort* __restrict__ qkv, const ushort* __restrict__ vt,
                ushort* __restrict__ obuf)
{
  __shared__ ushort lK[64 * 64];    // [kv][d]
  __shared__ ushort lVt[64 * 64];   // [d][kv]
  __shared__ ushort lP[4 * 32 * 64]; // per-wave [q][kv]
  const int tid = threadIdx.x;
  const int w = tid >> 6, lane = tid & 63;
  const int g = lane >> 4, c = lane & 15;
  const int bh = blockIdx.y, b = bh >> 4, h = bh & 15;
  const int qw = blockIdx.x * 128 + w * 32;
  const float c8 = 0.18033688f;     // log2(e)/8  -> softmax(s/8)

  s16x8 qfr[2][2];
#pragma unroll
  for (int qf = 0; qf < 2; ++qf)
#pragma unroll
    for (int ds = 0; ds < 2; ++ds)
      qfr[qf][ds] = *(const s16x8*)(qkv
          + (long)((b << 10) + qw + qf * 16 + c) * 3072 + (h << 6) + ds * 32 + g * 8);

  f32x4 acc_o[2][4] = {};
  float m[2][4], l[2][4];
#pragma unroll
  for (int qf = 0; qf < 2; ++qf)
#pragma unroll
    for (int j = 0; j < 4; ++j) { m[qf][j] = -3.0e38f; l[qf][j] = 0.f; }

  ushort* lPw = &lP[w * 2048];

  for (int t = 0; t < 16; ++t) {
    const int kv0 = t * 64;
#pragma unroll
    for (int i = 0; i < 2; ++i) {
      int idx = i * TPB + tid;
      int r = idx >> 3, dc = (idx & 7) * 8;
      gload_lds16(qkv + (long)((b << 10) + kv0 + r) * 3072 + 1024 + (h << 6) + dc,
                  &lK[idx * 8]);
    }
#pragma unroll
    for (int i = 0; i < 2; ++i) {
      int idx = i * TPB + tid;
      int r = idx >> 3, dc = (idx & 7) * 8;
      gload_lds16(vt + (long)((bh << 6) + r) * 1024 + kv0 + dc, &lVt[idx * 8]);
    }
    __syncthreads();

    f32x4 s[2][4] = {};
#pragma unroll
    for (int ds = 0; ds < 2; ++ds) {
      s16x8 bk[4];
#pragma unroll
      for (int kf = 0; kf < 4; ++kf)
        bk[kf] = *(const s16x8*)&lK[(kf * 16 + c) * 64 + ds * 32 + g * 8];
#pragma unroll
      for (int qf = 0; qf < 2; ++qf)
#pragma unroll
        for (int kf = 0; kf < 4; ++kf)
          s[qf][kf] = __builtin_amdgcn_mfma_f32_16x16x32_bf16(qfr[qf][ds], bk[kf], s[qf][kf], 0, 0, 0);
    }

#pragma unroll
    for (int qf = 0; qf < 2; ++qf)
#pragma unroll
      for (int j = 0; j < 4; ++j) {
        float tm = fmaxf(fmaxf(s[qf][0][j], s[qf][1][j]), fmaxf(s[qf][2][j], s[qf][3][j]));
        tm = fmaxf(tm, __shfl_xor(tm, 1));
        tm = fmaxf(tm, __shfl_xor(tm, 2));
        tm = fmaxf(tm, __shfl_xor(tm, 4));
        tm = fmaxf(tm, __shfl_xor(tm, 8));
        float mn = fmaxf(m[qf][j], tm);
        float scale = exp2f((m[qf][j] - mn) * c8);
        m[qf][j] = mn;
        l[qf][j] *= scale;
#pragma unroll
        for (int df = 0; df < 4; ++df) acc_o[qf][df][j] *= scale;
        float ps = 0.f;
#pragma unroll
        for (int kf = 0; kf < 4; ++kf) {
          float pv = exp2f((s[qf][kf][j] - mn) * c8);
          ps += pv;
          lPw[(qf * 16 + g * 4 + j) * 64 + kf * 16 + c] = f2bf(pv);
        }
        l[qf][j] += ps;
      }

#pragma unroll
    for (int kvb = 0; kvb < 2; ++kvb) {
      s16x8 pA[2], vB[4];
#pragma unroll
      for (int qf = 0; qf < 2; ++qf)
        pA[qf] = *(const s16x8*)&lPw[(qf * 16 + c) * 64 + kvb * 32 + g * 8];
#pragma unroll
      for (int df = 0; df < 4; ++df)
        vB[df] = *(const s16x8*)&lVt[(df * 16 + c) * 64 + kvb * 32 + g * 8];
#pragma unroll
      for (int qf = 0; qf < 2; ++qf)
#pragma unroll
        for (int df = 0; df < 4; ++df)
          acc_o[qf][df] = __builtin_amdgcn_mfma_f32_16x16x32_bf16(pA[qf], vB[df], acc_o[qf][df], 0, 0, 0);
    }
    __syncthreads();
  }

#pragma unroll
  for (int qf = 0; qf < 2; ++qf)
#pragma unroll
    for (int j = 0; j < 4; ++j) {
      float lv = l[qf][j];
      lv += __shfl_xor(lv, 1);
      lv += __shfl_xor(lv, 2);
      lv += __shfl_xor(lv, 4);
      lv += __shfl_xor(lv, 8);
      float inv = 1.f / lv;
#pragma unroll
      for (int df = 0; df < 4; ++df)
        obuf[(long)((b << 10) + qw + qf * 16 + g * 4 + j) * 1024 + (h << 6) + df * 16 + c]
            = f2bf(acc_o[qf][df][j] * inv);
    }
}

// LayerNorm (torch variant: unbiased std, eps added to std). One block per row.
template<bool OBF>
__global__ __launch_bounds__(TPB)
void ln_rows(const float* __restrict__ X, const float* __restrict__ ga,
             const float* __restrict__ gb, void* __restrict__ out)
{
  __shared__ float red[4];
  const int tid = threadIdx.x;
  const long base = (long)blockIdx.x * 1024;
  f32x4 v = *(const f32x4*)&X[base + tid * 4];
  float mean = blk_sum(v[0] + v[1] + v[2] + v[3], red, tid) * (1.f / 1024.f);
  f32x4 d = v - mean;
  float qs = blk_sum(d[0]*d[0] + d[1]*d[1] + d[2]*d[2] + d[3]*d[3], red, tid);
  float inv = 1.f / (sqrtf(qs * (1.f / 1023.f)) + 1e-6f);
  f32x4 a4 = *(const f32x4*)&ga[tid * 4];
  f32x4 b4 = *(const f32x4*)&gb[tid * 4];
  f32x4 r = a4 * (d * inv) + b4;
  if (OBF) {
    ushort4 o4 = { f2bf(r[0]), f2bf(r[1]), f2bf(r[2]), f2bf(r[3]) };
    *(ushort4*)((ushort*)out + base + tid * 4) = o4;
  } else {
    *(f32x4*)((float*)out + base + tid * 4) = r;
  }
}

// vt[b*16+h][d=64][kv=1024] = qkv[(b*1024+kv)*3072 + 2048 + h*64 + d]
__global__ __launch_bounds__(TPB)
void vt_build(const ushort* __restrict__ qkv, ushort* __restrict__ vt)
{
  __shared__ ushort t[64][72];
  const int tid = threadIdx.x;
  const int bh = blockIdx.y, b = bh >> 4, h = bh & 15;
  const int kv0 = blockIdx.x * 64;
#pragma unroll
  for (int it = 0; it < 2; ++it) {
    int idx = (it * TPB + tid) * 8;
    int r = idx >> 6, cc = idx & 63;
    s16x8 v = *(const s16x8*)(qkv + ((long)((b << 10) + kv0 + r)) * 3072 + 2048 + (h << 6) + cc);
#pragma unroll
    for (int j = 0; j < 8; ++j) t[r][cc + j] = (ushort)v[j];
  }
  __syncthreads();
#pragma unroll
  for (int it = 0; it < 2; ++it) {
    int idx = (it * TPB + tid) * 8;
    int dd = idx >> 6, kvo = idx & 63;
    ushort tmp[8];
#pragma unroll
    for (int j = 0; j < 8; ++j) tmp[j] = t[kvo + j][dd];
    *(s16x8*)(vt + ((long)bh * 64 + dd) * 1024 + kv0 + kvo) = *(const s16x8*)tmp;
  }
}

// weight prep ---------------------------------------------------------------
__global__ __launch_bounds__(TPB)
void wt_build(const float* __restrict__ in, ushort* __restrict__ out)
{
  __shared__ float t[64][65];
  const int tid = threadIdx.x;
  const int k0 = blockIdx.x * 64, n0 = blockIdx.y * 64;
#pragma unroll
  for (int it = 0; it < 4; ++it) {
    int idx = it * TPB + tid;
    int r = idx >> 4, c4 = (idx & 15) * 4;
    f32x4 v = *(const f32x4*)&in[(long)(k0 + r) * 1024 + n0 + c4];
    t[r][c4] = v[0]; t[r][c4 + 1] = v[1]; t[r][c4 + 2] = v[2]; t[r][c4 + 3] = v[3];
  }
  __syncthreads();
#pragma unroll
  for (int it = 0; it < 4; ++it) {
    int idx = it * TPB + tid;
    int nr = idx >> 4, k4 = (idx & 15) * 4;
    ushort4 o = { f2bf(t[k4][nr]), f2bf(t[k4 + 1][nr]),
                  f2bf(t[k4 + 2][nr]), f2bf(t[k4 + 3][nr]) };
    *(ushort4*)&out[(long)(n0 + nr) * 1024 + k0 + k4] = o;
  }
}
// per-oi: read w[oi*f .. +f) contiguously, scatter to f tap matrices (coalesced)
__global__ __launch_bounds__(TPB)
void tap_build(const float* __restrict__ w, ushort* __restrict__ out, int f)
{
  long oi = (long)blockIdx.x * TPB + threadIdx.x;
  for (int t = 0; t < f; ++t)
    out[(long)t * 1048576 + oi] = f2bf(w[oi * f + t]);
}
__global__ __launch_bounds__(TPB)
void bn_prep(const float* __restrict__ cb, const float* __restrict__ g,
             const float* __restrict__ bb, const float* __restrict__ m,
             const float* __restrict__ v, float* __restrict__ sc, float* __restrict__ sh)
{
  int i = blockIdx.x * TPB + threadIdx.x;
  float s = g[i] * rsqrtf(v[i] + 1e-5f);
  sc[i] = s;
  sh[i] = (cb[i] - m[i]) * s + bb[i];
}
__global__ __launch_bounds__(TPB)
void qkvb_build(const float* __restrict__ bq, const float* __restrict__ bk,
                const float* __restrict__ bv, float* __restrict__ out)
{
  int i = blockIdx.x * TPB + threadIdx.x;
  out[i] = (i < 1024) ? bq[i] : (i < 2048 ? bk[i - 1024] : bv[i - 2048]);
}
__global__ void zero_ws(ushort* z) { z[threadIdx.x] = 0; }

// ---------------------------------------------------------------------------
extern "C" void kernel_launch(void* const* d_in, const int* in_sizes, int n_in,
                              void* d_out, int out_size, void* d_ws, size_t ws_size,
                              hipStream_t stream)
{
  const float* X  = (const float*)d_in[0];
  const float* Wq = (const float*)d_in[1];
  const float* Wk = (const float*)d_in[2];
  const float* Wv = (const float*)d_in[3];
  const float* Wo = (const float*)d_in[4];
  const float* Bq = (const float*)d_in[5];
  const float* Bk = (const float*)d_in[6];
  const float* Bv = (const float*)d_in[7];
  const float* Bo = (const float*)d_in[8];
  const float *CW[3], *CB[3], *BG[3], *BBe[3], *BMu[3], *BVa[3];
  for (int i = 0; i < 3; ++i) {
    CW[i]  = (const float*)d_in[9 + 6 * i];
    CB[i]  = (const float*)d_in[10 + 6 * i];
    BG[i]  = (const float*)d_in[11 + 6 * i];
    BBe[i] = (const float*)d_in[12 + 6 * i];
    BMu[i] = (const float*)d_in[13 + 6 * i];
    BVa[i] = (const float*)d_in[14 + 6 * i];
  }
  const float* L1a = (const float*)d_in[27];
  const float* L2a = (const float*)d_in[28];
  const float* LFa = (const float*)d_in[29];
  const float* L1b = (const float*)d_in[30];
  const float* L2b = (const float*)d_in[31];
  const float* LFb = (const float*)d_in[32];

  char* p = (char*)d_ws;
  auto carve = [&](size_t bytes) { char* r = p; p += (bytes + 255) & ~(size_t)255; return r; };
  ushort* abuf  = (ushort*)carve(16777216);   // LN out bf16 [8192][1024]
  ushort* wqkvt = (ushort*)carve(6291456);
  ushort* wot   = (ushort*)carve(2097152);
  ushort* wtap  = (ushort*)carve(18874368);   // 9 taps [1024,1024] bf16
  ushort* qkv   = (ushort*)carve(50331648);   // bf16 [8192][3072]
  ushort* vt    = (ushort*)carve(16777216);   // V^T bf16 [128][64][1024]
  ushort* obuf  = (ushort*)carve(16777216);   // attn out bf16 [8192][1024]
  float*  qkvb  = (float*) carve(12288);
  float*  bnsc  = (float*) carve(12288);
  float*  bnsh  = (float*) carve(12288);
  ushort* zp    = (ushort*)carve(256);
  if ((size_t)(p - (char*)d_ws) > ws_size) return;  // ~123 MB; known to fit

  float* xbuf = (float*)d_out;                // residual stream lives in d_out

  // per-call weight prep (graph-safe: identical work every call)
  wt_build<<<dim3(16, 16), TPB, 0, stream>>>(Wq, wqkvt);
  wt_build<<<dim3(16, 16), TPB, 0, stream>>>(Wk, wqkvt + 1048576);
  wt_build<<<dim3(16, 16), TPB, 0, stream>>>(Wv, wqkvt + 2097152);
  wt_build<<<dim3(16, 16), TPB, 0, stream>>>(Wo, wot);
  tap_build<<<4096, TPB, 0, stream>>>(CW[0], wtap, 1);
  tap_build<<<4096, TPB, 0, stream>>>(CW[1], wtap + 1048576, 3);
  tap_build<<<4096, TPB, 0, stream>>>(CW[2], wtap + 4 * 1048576, 5);
  for (int i = 0; i < 3; ++i)
    bn_prep<<<4, TPB, 0, stream>>>(CB[i], BG[i], BBe[i], BMu[i], BVa[i],
                                   bnsc + i * 1024, bnsh + i * 1024);
  qkvb_build<<<12, TPB, 0, stream>>>(Bq, Bk, Bv, qkvb);
  zero_ws<<<1, 128, 0, stream>>>(zp);

  for (int L = 0; L < 2; ++L) {
    const float* xs = (L == 0) ? X : xbuf;
    // ---- x + MHA(LN1(x)) ----
    ln_rows<true><<<8192, TPB, 0, stream>>>(xs, L1a, L1b, abuf);
    gemm_bt<true, true, false><<<dim3(64, 24), TPB, 0, stream>>>(
        abuf, 1024, wqkvt, 1024, qkv, 3072, qkvb, nullptr, 1024);
    vt_build<<<dim3(16, 128), TPB, 0, stream>>>(qkv, vt);
    flash_attn<<<dim3(8, 128), TPB, 0, stream>>>(qkv, vt, obuf);
    gemm_bt<false, true, true><<<dim3(64, 8), TPB, 0, stream>>>(
        obuf, 1024, wot, 1024, xbuf, 1024, Bo, xs, 1024);
    // ---- x + FFN(LN2(x)): one fused deep-pipelined dispatch ----
    ln_rows<true><<<8192, TPB, 0, stream>>>(xbuf, L2a, L2b, abuf);
    conv_fused2<<<dim3(32, 8), 512, 147456, stream>>>(abuf, wtap, xbuf, bnsc, bnsh, zp);
  }
  ln_rows<false><<<8192, TPB, 0, stream>>>(xbuf, LFa, LFb, d_out);
}

// Round 8
// 990.569 us; speedup vs baseline: 2.0165x; 1.0342x over previous
//
#include <hip/hip_runtime.h>

#define TPB 256

typedef __attribute__((ext_vector_type(4))) float f32x4;
typedef __attribute__((ext_vector_type(8))) short s16x8;

__device__ __forceinline__ ushort f2bf(float f) {
  unsigned x = __float_as_uint(f);
  return (ushort)((x + 0x7fffu + ((x >> 16) & 1u)) >> 16);
}
__device__ __forceinline__ float b2f(ushort u) {
  return __uint_as_float(((unsigned)u) << 16);
}
__device__ __forceinline__ void gload_lds16(const ushort* g, ushort* l) {
  __builtin_amdgcn_global_load_lds(
      (const __attribute__((address_space(1))) void*)g,
      (__attribute__((address_space(3))) void*)l, 16, 0, 0);
}

__device__ __forceinline__ float blk_sum(float v, float* red, int tid) {
#pragma unroll
  for (int o = 32; o; o >>= 1) v += __shfl_xor(v, o);
  if ((tid & 63) == 0) red[tid >> 6] = v;
  __syncthreads();
  float r = red[0] + red[1] + red[2] + red[3];
  __syncthreads();
  return r;
}

// ---------------------------------------------------------------------------
// GEMM: C[M,N] = A[M,K](bf16) @ Bt[N,K]^T(bf16)  (+bias, +residual)
// 128x128 tile, BK=32, 4 waves 2x2, 16x16x32 bf16 MFMA.
// ---------------------------------------------------------------------------
template<bool C_BF16, bool HAS_BIAS, bool HAS_RES>
__global__ __launch_bounds__(TPB, 2)
void gemm_bt(const ushort* __restrict__ A, int lda,
             const ushort* __restrict__ B, int ldb,
             void* __restrict__ Cp, int ldc,
             const float* __restrict__ bias, const float* __restrict__ Res, int K)
{
  constexpr int BM = 128, BK = 32;
  __shared__ ushort lA[BM * BK];
  __shared__ ushort lB[128 * BK];
  const int tid = threadIdx.x;
  const int rowBase = blockIdx.x * BM;
  const int colBase = blockIdx.y * 128;
  const int w = tid >> 6, lane = tid & 63;
  const int wr = w >> 1, wc = w & 1;
  const int lr = lane & 15, lk = (lane >> 4) * 8;

  f32x4 acc[4][4] = {};

  for (int k0 = 0; k0 < K; k0 += BK) {
#pragma unroll
    for (int i = 0; i < 2; ++i) {
      int idx = i * TPB + tid;
      int r = idx >> 2, kk = (idx & 3) * 8;
      gload_lds16(A + (long)(rowBase + r) * lda + k0 + kk, &lA[idx * 8]);
    }
#pragma unroll
    for (int i = 0; i < 2; ++i) {
      int idx = i * TPB + tid;
      int r = idx >> 2, kk = (idx & 3) * 8;
      gload_lds16(B + (long)(colBase + r) * ldb + k0 + kk, &lB[idx * 8]);
    }
    __syncthreads();
    s16x8 af[4], bfr[4];
#pragma unroll
    for (int m = 0; m < 4; ++m)
      af[m] = *(const s16x8*)&lA[(wr * 64 + m * 16 + lr) * BK + lk];
#pragma unroll
    for (int n = 0; n < 4; ++n)
      bfr[n] = *(const s16x8*)&lB[(wc * 64 + n * 16 + lr) * BK + lk];
#pragma unroll
    for (int m = 0; m < 4; ++m)
#pragma unroll
      for (int n = 0; n < 4; ++n)
        acc[m][n] = __builtin_amdgcn_mfma_f32_16x16x32_bf16(af[m], bfr[n], acc[m][n], 0, 0, 0);
    __syncthreads();
  }

  const int crow0 = rowBase + wr * 64 + (lane >> 4) * 4;
#pragma unroll
  for (int m = 0; m < 4; ++m) {
#pragma unroll
    for (int n = 0; n < 4; ++n) {
      const int ccol = colBase + wc * 64 + n * 16 + lr;
      const float bv = HAS_BIAS ? bias[ccol] : 0.f;
#pragma unroll
      for (int j = 0; j < 4; ++j) {
        const long off = (long)(crow0 + m * 16 + j) * ldc + ccol;
        float v = acc[m][n][j] + bv;
        if (HAS_RES) v += Res[off];
        if (C_BF16) ((ushort*)Cp)[off] = f2bf(v);
        else        ((float*)Cp)[off] = v;
      }
    }
  }
}

// ---------------------------------------------------------------------------
// Fused conv FFN v2 + T5: x += mean_br relu(bn_br(conv_br(A))).
// BM=256 x BN=128, BK=64, 8 waves (4Mx2N), grid 256 = 1/CU, triple-buffered
// LDS, counted vmcnt(6), slot-XOR swizzle (0 bank conflicts, verified R6).
// R7: s_setprio(1/0) around each 16-MFMA half-K cluster (T5).
// ---------------------------------------------------------------------------
__global__ __launch_bounds__(512, 2)
void conv_fused2(const ushort* __restrict__ A, const ushort* __restrict__ W9,
                 float* __restrict__ x, const float* __restrict__ sc,
                 const float* __restrict__ sh, const ushort* __restrict__ zp)
{
  extern __shared__ ushort smem[];      // [3][256*64] A + [3][128*64] B
  ushort* lA = smem;                    // 3 * 16384 ushorts
  ushort* lB = smem + 49152;            // 3 * 8192 ushorts
  const int tid = threadIdx.x;
  const int rowBase = blockIdx.x * 256;
  const int colBase = blockIdx.y * 128;
  const int w = tid >> 6, lane = tid & 63;
  const int wrm = w >> 1, wcn = w & 1;  // 4Mx2N wave grid
  const int lr = lane & 15, kg = lane >> 4;

  f32x4 acc[4][4] = {};
  f32x4 res[4][4] = {};

  auto stage = [&](int t, int buf) {
    const int s = t >> 4;                                   // segment 0..8
    const int k0 = (t & 15) * 64;
    const int shift = (s == 0) ? 0 : ((s <= 3) ? s - 2 : s - 6);
    const ushort* Wseg = W9 + (long)s * 1048576 + k0;
    const ushort* Ak = A + k0;
    ushort* dA = lA + buf * 16384;
    ushort* dB = lB + buf * 8192;
#pragma unroll
    for (int i = 0; i < 4; ++i) {       // A: 256 rows x 8 slots, 4 issues
      int li = i * 512 + tid;
      int r = li >> 3, sl = li & 7;
      int gsl = sl ^ (r & 7);           // inverse-swizzled global slot
      int gr = rowBase + r;
      int sr = (gr & 1023) + shift;
      const ushort* src = ((unsigned)sr < 1024u)
          ? (Ak + (long)((gr & ~1023) + sr) * 1024 + gsl * 8) : zp;
      gload_lds16(src, dA + li * 8);
    }
#pragma unroll
    for (int i = 0; i < 2; ++i) {       // B: 128 rows x 8 slots, 2 issues
      int li = i * 512 + tid;
      int r = li >> 3, sl = li & 7;
      int gsl = sl ^ (r & 7);
      gload_lds16(Wseg + (long)(colBase + r) * 1024 + gsl * 8, dB + li * 8);
    }
  };

  // prologue: fill buffers 0,1; wait for buffer 0 (6 of 12 loads drained)
  stage(0, 0);
  stage(1, 1);
  __builtin_amdgcn_sched_barrier(0);
  asm volatile("s_waitcnt vmcnt(6)" ::: "memory");
  __builtin_amdgcn_sched_barrier(0);
  __syncthreads();

#pragma unroll 3
  for (int t = 0; t < 144; ++t) {
    const int cur = t % 3;
    if (t + 2 < 144) stage(t + 2, (t + 2) % 3);

    const ushort* bA = lA + cur * 16384;
    const ushort* bB = lB + cur * 8192;
#pragma unroll
    for (int ks = 0; ks < 2; ++ks) {    // two K=32 halves of BK=64
      s16x8 af[4], bfr[4];
#pragma unroll
      for (int mf = 0; mf < 4; ++mf) {
        int r = wrm * 64 + mf * 16 + lr;
        int sl = (ks * 4 + kg) ^ (r & 7);
        af[mf] = *(const s16x8*)&bA[r * 64 + sl * 8];
      }
#pragma unroll
      for (int nf = 0; nf < 4; ++nf) {
        int r = wcn * 64 + nf * 16 + lr;
        int sl = (ks * 4 + kg) ^ (r & 7);
        bfr[nf] = *(const s16x8*)&bB[r * 64 + sl * 8];
      }
      __builtin_amdgcn_s_setprio(1);
#pragma unroll
      for (int mf = 0; mf < 4; ++mf)
#pragma unroll
        for (int nf = 0; nf < 4; ++nf)
          acc[mf][nf] = __builtin_amdgcn_mfma_f32_16x16x32_bf16(af[mf], bfr[nf], acc[mf][nf], 0, 0, 0);
      __builtin_amdgcn_s_setprio(0);
    }

    if (t == 15 || t == 63 || t == 143) {     // branch boundary fold
      const int br = (t == 15) ? 0 : (t == 63 ? 1 : 2);
#pragma unroll
      for (int nf = 0; nf < 4; ++nf) {
        const int col = colBase + wcn * 64 + nf * 16 + lr;
        const float scv = sc[br * 1024 + col];
        const float shv = sh[br * 1024 + col];
#pragma unroll
        for (int mf = 0; mf < 4; ++mf)
#pragma unroll
          for (int j = 0; j < 4; ++j) {
            res[mf][nf][j] += fmaxf(acc[mf][nf][j] * scv + shv, 0.f);
            acc[mf][nf][j] = 0.f;
          }
      }
    }

    // drain: stage(t+1) must be in LDS before next step (stage(t+2) stays in flight)
    __builtin_amdgcn_sched_barrier(0);
    if (t + 2 < 144)      asm volatile("s_waitcnt vmcnt(6)" ::: "memory");
    else if (t + 1 < 144) asm volatile("s_waitcnt vmcnt(0)" ::: "memory");
    __builtin_amdgcn_sched_barrier(0);
    __syncthreads();
  }

  const int crow0 = rowBase + wrm * 64 + kg * 4;
#pragma unroll
  for (int mf = 0; mf < 4; ++mf)
#pragma unroll
    for (int nf = 0; nf < 4; ++nf) {
      const int col = colBase + wcn * 64 + nf * 16 + lr;
#pragma unroll
      for (int j = 0; j < 4; ++j) {
        const long off = (long)(crow0 + mf * 16 + j) * 1024 + col;
        x[off] += res[mf][nf][j] * (1.f / 3.f);
      }
    }
}

// ---------------------------------------------------------------------------
// Flash attention v2: grid (8 q-tiles, 128 bh), 4 waves x 32 q-rows, KV=64.
// KV double-buffered: per tile {stage(t+1) -> compute(buf t&1) -> vmcnt(0) ->
// barrier} (1 barrier/tile; prefetch hides under QK+softmax+PV). setprio
// around MFMA clusters. Race arg: stage(t+1) writes parity (t+1)&1 whose last
// reads (iter t-1) completed before the end-of-(t-1) barrier; stage(t)
// visibility from end-of-(t-1) vmcnt(0)+barrier.
// ---------------------------------------------------------------------------
__global__ __launch_bounds__(TPB)
void flash_attn(const ushort* __restrict__ qkv, const ushort* __restrict__ vt,
                ushort* __restrict__ obuf)
{
  __shared__ ushort lK[2][64 * 64];   // [pb][kv][d]
  __shared__ ushort lVt[2][64 * 64];  // [pb][d][kv]
  __shared__ ushort lP[4 * 32 * 64];  // per-wave [q][kv]
  const int tid = threadIdx.x;
  const int w = tid >> 6, lane = tid & 63;
  const int g = lane >> 4, c = lane & 15;
  const int bh = blockIdx.y, b = bh >> 4, h = bh & 15;
  const int qw = blockIdx.x * 128 + w * 32;
  const float c8 = 0.18033688f;       // log2(e)/8  -> softmax(s/8)

  auto stage = [&](int t, int pb) {
    const int kv0 = t * 64;
#pragma unroll
    for (int i = 0; i < 2; ++i) {     // K tile: [kv][64]
      int idx = i * TPB + tid;
      int r = idx >> 3, dc = (idx & 7) * 8;
      gload_lds16(qkv + (long)((b << 10) + kv0 + r) * 3072 + 1024 + (h << 6) + dc,
                  &lK[pb][idx * 8]);
    }
#pragma unroll
    for (int i = 0; i < 2; ++i) {     // V^T tile: [d][64]
      int idx = i * TPB + tid;
      int r = idx >> 3, dc = (idx & 7) * 8;
      gload_lds16(vt + (long)((bh << 6) + r) * 1024 + kv0 + dc, &lVt[pb][idx * 8]);
    }
  };

  s16x8 qfr[2][2];
#pragma unroll
  for (int qf = 0; qf < 2; ++qf)
#pragma unroll
    for (int ds = 0; ds < 2; ++ds)
      qfr[qf][ds] = *(const s16x8*)(qkv
          + (long)((b << 10) + qw + qf * 16 + c) * 3072 + (h << 6) + ds * 32 + g * 8);

  f32x4 acc_o[2][4] = {};
  float m[2][4], l[2][4];
#pragma unroll
  for (int qf = 0; qf < 2; ++qf)
#pragma unroll
    for (int j = 0; j < 4; ++j) { m[qf][j] = -3.0e38f; l[qf][j] = 0.f; }

  ushort* lPw = &lP[w * 2048];

  // prologue
  stage(0, 0);
  __builtin_amdgcn_sched_barrier(0);
  asm volatile("s_waitcnt vmcnt(0)" ::: "memory");
  __builtin_amdgcn_sched_barrier(0);
  __syncthreads();

  for (int t = 0; t < 16; ++t) {
    const int pb = t & 1;
    if (t + 1 < 16) stage(t + 1, pb ^ 1);

    // S = Q @ K^T : C[row=q, col=kv]
    f32x4 s[2][4] = {};
#pragma unroll
    for (int ds = 0; ds < 2; ++ds) {
      s16x8 bk[4];
#pragma unroll
      for (int kf = 0; kf < 4; ++kf)
        bk[kf] = *(const s16x8*)&lK[pb][(kf * 16 + c) * 64 + ds * 32 + g * 8];
      __builtin_amdgcn_s_setprio(1);
#pragma unroll
      for (int qf = 0; qf < 2; ++qf)
#pragma unroll
        for (int kf = 0; kf < 4; ++kf)
          s[qf][kf] = __builtin_amdgcn_mfma_f32_16x16x32_bf16(qfr[qf][ds], bk[kf], s[qf][kf], 0, 0, 0);
      __builtin_amdgcn_s_setprio(0);
    }

    // online softmax; row q = qf*16 + g*4 + j spans the 16 c-lanes
#pragma unroll
    for (int qf = 0; qf < 2; ++qf)
#pragma unroll
      for (int j = 0; j < 4; ++j) {
        float tm = fmaxf(fmaxf(s[qf][0][j], s[qf][1][j]), fmaxf(s[qf][2][j], s[qf][3][j]));
        tm = fmaxf(tm, __shfl_xor(tm, 1));
        tm = fmaxf(tm, __shfl_xor(tm, 2));
        tm = fmaxf(tm, __shfl_xor(tm, 4));
        tm = fmaxf(tm, __shfl_xor(tm, 8));
        float mn = fmaxf(m[qf][j], tm);
        float scale = exp2f((m[qf][j] - mn) * c8);
        m[qf][j] = mn;
        l[qf][j] *= scale;
#pragma unroll
        for (int df = 0; df < 4; ++df) acc_o[qf][df][j] *= scale;
        float ps = 0.f;
#pragma unroll
        for (int kf = 0; kf < 4; ++kf) {
          float pv = exp2f((s[qf][kf][j] - mn) * c8);
          ps += pv;
          lPw[(qf * 16 + g * 4 + j) * 64 + kf * 16 + c] = f2bf(pv);
        }
        l[qf][j] += ps;   // lane-partial over kv ≡ c (mod 16); reduced at end
      }

    // O += P @ V : A[row=q, k=kv] from lPw, B[col=d, k=kv] from lVt
#pragma unroll
    for (int kvb = 0; kvb < 2; ++kvb) {
      s16x8 pA[2], vB[4];
#pragma unroll
      for (int qf = 0; qf < 2; ++qf)
        pA[qf] = *(const s16x8*)&lPw[(qf * 16 + c) * 64 + kvb * 32 + g * 8];
#pragma unroll
      for (int df = 0; df < 4; ++df)
        vB[df] = *(const s16x8*)&lVt[pb][(df * 16 + c) * 64 + kvb * 32 + g * 8];
      __builtin_amdgcn_s_setprio(1);
#pragma unroll
      for (int qf = 0; qf < 2; ++qf)
#pragma unroll
        for (int df = 0; df < 4; ++df)
          acc_o[qf][df] = __builtin_amdgcn_mfma_f32_16x16x32_bf16(pA[qf], vB[df], acc_o[qf][df], 0, 0, 0);
      __builtin_amdgcn_s_setprio(0);
    }

    __builtin_amdgcn_sched_barrier(0);
    asm volatile("s_waitcnt vmcnt(0)" ::: "memory");
    __builtin_amdgcn_sched_barrier(0);
    __syncthreads();
  }

#pragma unroll
  for (int qf = 0; qf < 2; ++qf)
#pragma unroll
    for (int j = 0; j < 4; ++j) {
      float lv = l[qf][j];
      lv += __shfl_xor(lv, 1);
      lv += __shfl_xor(lv, 2);
      lv += __shfl_xor(lv, 4);
      lv += __shfl_xor(lv, 8);
      float inv = 1.f / lv;
#pragma unroll
      for (int df = 0; df < 4; ++df)
        obuf[(long)((b << 10) + qw + qf * 16 + g * 4 + j) * 1024 + (h << 6) + df * 16 + c]
            = f2bf(acc_o[qf][df][j] * inv);
    }
}

// LayerNorm (torch variant: unbiased std, eps added to std). One block per row.
template<bool OBF>
__global__ __launch_bounds__(TPB)
void ln_rows(const float* __restrict__ X, const float* __restrict__ ga,
             const float* __restrict__ gb, void* __restrict__ out)
{
  __shared__ float red[4];
  const int tid = threadIdx.x;
  const long base = (long)blockIdx.x * 1024;
  f32x4 v = *(const f32x4*)&X[base + tid * 4];
  float mean = blk_sum(v[0] + v[1] + v[2] + v[3], red, tid) * (1.f / 1024.f);
  f32x4 d = v - mean;
  float qs = blk_sum(d[0]*d[0] + d[1]*d[1] + d[2]*d[2] + d[3]*d[3], red, tid);
  float inv = 1.f / (sqrtf(qs * (1.f / 1023.f)) + 1e-6f);
  f32x4 a4 = *(const f32x4*)&ga[tid * 4];
  f32x4 b4 = *(const f32x4*)&gb[tid * 4];
  f32x4 r = a4 * (d * inv) + b4;
  if (OBF) {
    ushort4 o4 = { f2bf(r[0]), f2bf(r[1]), f2bf(r[2]), f2bf(r[3]) };
    *(ushort4*)((ushort*)out + base + tid * 4) = o4;
  } else {
    *(f32x4*)((float*)out + base + tid * 4) = r;
  }
}

// vt[b*16+h][d=64][kv=1024] = qkv[(b*1024+kv)*3072 + 2048 + h*64 + d]
__global__ __launch_bounds__(TPB)
void vt_build(const ushort* __restrict__ qkv, ushort* __restrict__ vt)
{
  __shared__ ushort t[64][72];
  const int tid = threadIdx.x;
  const int bh = blockIdx.y, b = bh >> 4, h = bh & 15;
  const int kv0 = blockIdx.x * 64;
#pragma unroll
  for (int it = 0; it < 2; ++it) {
    int idx = (it * TPB + tid) * 8;
    int r = idx >> 6, cc = idx & 63;
    s16x8 v = *(const s16x8*)(qkv + ((long)((b << 10) + kv0 + r)) * 3072 + 2048 + (h << 6) + cc);
#pragma unroll
    for (int j = 0; j < 8; ++j) t[r][cc + j] = (ushort)v[j];
  }
  __syncthreads();
#pragma unroll
  for (int it = 0; it < 2; ++it) {
    int idx = (it * TPB + tid) * 8;
    int dd = idx >> 6, kvo = idx & 63;
    ushort tmp[8];
#pragma unroll
    for (int j = 0; j < 8; ++j) tmp[j] = t[kvo + j][dd];
    *(s16x8*)(vt + ((long)bh * 64 + dd) * 1024 + kv0 + kvo) = *(const s16x8*)tmp;
  }
}

// weight prep ---------------------------------------------------------------
__global__ __launch_bounds__(TPB)
void wt_build(const float* __restrict__ in, ushort* __restrict__ out)
{
  __shared__ float t[64][65];
  const int tid = threadIdx.x;
  const int k0 = blockIdx.x * 64, n0 = blockIdx.y * 64;
#pragma unroll
  for (int it = 0; it < 4; ++it) {
    int idx = it * TPB + tid;
    int r = idx >> 4, c4 = (idx & 15) * 4;
    f32x4 v = *(const f32x4*)&in[(long)(k0 + r) * 1024 + n0 + c4];
    t[r][c4] = v[0]; t[r][c4 + 1] = v[1]; t[r][c4 + 2] = v[2]; t[r][c4 + 3] = v[3];
  }
  __syncthreads();
#pragma unroll
  for (int it = 0; it < 4; ++it) {
    int idx = it * TPB + tid;
    int nr = idx >> 4, k4 = (idx & 15) * 4;
    ushort4 o = { f2bf(t[k4][nr]), f2bf(t[k4 + 1][nr]),
                  f2bf(t[k4 + 2][nr]), f2bf(t[k4 + 3][nr]) };
    *(ushort4*)&out[(long)(n0 + nr) * 1024 + k0 + k4] = o;
  }
}
// per-oi: read w[oi*f .. +f) contiguously, scatter to f tap matrices (coalesced)
__global__ __launch_bounds__(TPB)
void tap_build(const float* __restrict__ w, ushort* __restrict__ out, int f)
{
  long oi = (long)blockIdx.x * TPB + threadIdx.x;
  for (int t = 0; t < f; ++t)
    out[(long)t * 1048576 + oi] = f2bf(w[oi * f + t]);
}
__global__ __launch_bounds__(TPB)
void bn_prep(const float* __restrict__ cb, const float* __restrict__ g,
             const float* __restrict__ bb, const float* __restrict__ m,
             const float* __restrict__ v, float* __restrict__ sc, float* __restrict__ sh)
{
  int i = blockIdx.x * TPB + threadIdx.x;
  float s = g[i] * rsqrtf(v[i] + 1e-5f);
  sc[i] = s;
  sh[i] = (cb[i] - m[i]) * s + bb[i];
}
__global__ __launch_bounds__(TPB)
void qkvb_build(const float* __restrict__ bq, const float* __restrict__ bk,
                const float* __restrict__ bv, float* __restrict__ out)
{
  int i = blockIdx.x * TPB + threadIdx.x;
  out[i] = (i < 1024) ? bq[i] : (i < 2048 ? bk[i - 1024] : bv[i - 2048]);
}
__global__ void zero_ws(ushort* z) { z[threadIdx.x] = 0; }

// ---------------------------------------------------------------------------
extern "C" void kernel_launch(void* const* d_in, const int* in_sizes, int n_in,
                              void* d_out, int out_size, void* d_ws, size_t ws_size,
                              hipStream_t stream)
{
  const float* X  = (const float*)d_in[0];
  const float* Wq = (const float*)d_in[1];
  const float* Wk = (const float*)d_in[2];
  const float* Wv = (const float*)d_in[3];
  const float* Wo = (const float*)d_in[4];
  const float* Bq = (const float*)d_in[5];
  const float* Bk = (const float*)d_in[6];
  const float* Bv = (const float*)d_in[7];
  const float* Bo = (const float*)d_in[8];
  const float *CW[3], *CB[3], *BG[3], *BBe[3], *BMu[3], *BVa[3];
  for (int i = 0; i < 3; ++i) {
    CW[i]  = (const float*)d_in[9 + 6 * i];
    CB[i]  = (const float*)d_in[10 + 6 * i];
    BG[i]  = (const float*)d_in[11 + 6 * i];
    BBe[i] = (const float*)d_in[12 + 6 * i];
    BMu[i] = (const float*)d_in[13 + 6 * i];
    BVa[i] = (const float*)d_in[14 + 6 * i];
  }
  const float* L1a = (const float*)d_in[27];
  const float* L2a = (const float*)d_in[28];
  const float* LFa = (const float*)d_in[29];
  const float* L1b = (const float*)d_in[30];
  const float* L2b = (const float*)d_in[31];
  const float* LFb = (const float*)d_in[32];

  char* p = (char*)d_ws;
  auto carve = [&](size_t bytes) { char* r = p; p += (bytes + 255) & ~(size_t)255; return r; };
  ushort* abuf  = (ushort*)carve(16777216);   // LN out bf16 [8192][1024]
  ushort* wqkvt = (ushort*)carve(6291456);
  ushort* wot   = (ushort*)carve(2097152);
  ushort* wtap  = (ushort*)carve(18874368);   // 9 taps [1024,1024] bf16
  ushort* qkv   = (ushort*)carve(50331648);   // bf16 [8192][3072]
  ushort* vt    = (ushort*)carve(16777216);   // V^T bf16 [128][64][1024]
  ushort* obuf  = (ushort*)carve(16777216);   // attn out bf16 [8192][1024]
  float*  qkvb  = (float*) carve(12288);
  float*  bnsc  = (float*) carve(12288);
  float*  bnsh  = (float*) carve(12288);
  ushort* zp    = (ushort*)carve(256);
  if ((size_t)(p - (char*)d_ws) > ws_size) return;  // ~123 MB; known to fit

  float* xbuf = (float*)d_out;                // residual stream lives in d_out

  // per-call weight prep (graph-safe: identical work every call)
  wt_build<<<dim3(16, 16), TPB, 0, stream>>>(Wq, wqkvt);
  wt_build<<<dim3(16, 16), TPB, 0, stream>>>(Wk, wqkvt + 1048576);
  wt_build<<<dim3(16, 16), TPB, 0, stream>>>(Wv, wqkvt + 2097152);
  wt_build<<<dim3(16, 16), TPB, 0, stream>>>(Wo, wot);
  tap_build<<<4096, TPB, 0, stream>>>(CW[0], wtap, 1);
  tap_build<<<4096, TPB, 0, stream>>>(CW[1], wtap + 1048576, 3);
  tap_build<<<4096, TPB, 0, stream>>>(CW[2], wtap + 4 * 1048576, 5);
  for (int i = 0; i < 3; ++i)
    bn_prep<<<4, TPB, 0, stream>>>(CB[i], BG[i], BBe[i], BMu[i], BVa[i],
                                   bnsc + i * 1024, bnsh + i * 1024);
  qkvb_build<<<12, TPB, 0, stream>>>(Bq, Bk, Bv, qkvb);
  zero_ws<<<1, 128, 0, stream>>>(zp);

  for (int L = 0; L < 2; ++L) {
    const float* xs = (L == 0) ? X : xbuf;
    // ---- x + MHA(LN1(x)) ----
    ln_rows<true><<<8192, TPB, 0, stream>>>(xs, L1a, L1b, abuf);
    gemm_bt<true, true, false><<<dim3(64, 24), TPB, 0, stream>>>(
        abuf, 1024, wqkvt, 1024, qkv, 3072, qkvb, nullptr, 1024);
    vt_build<<<dim3(16, 128), TPB, 0, stream>>>(qkv, vt);
    flash_attn<<<dim3(8, 128), TPB, 0, stream>>>(qkv, vt, obuf);
    gemm_bt<false, true, true><<<dim3(64, 8), TPB, 0, stream>>>(
        obuf, 1024, wot, 1024, xbuf, 1024, Bo, xs, 1024);
    // ---- x + FFN(LN2(x)): one fused deep-pipelined dispatch ----
    ln_rows<true><<<8192, TPB, 0, stream>>>(xbuf, L2a, L2b, abuf);
    conv_fused2<<<dim3(32, 8), 512, 147456, stream>>>(abuf, wtap, xbuf, bnsc, bnsh, zp);
  }
  ln_rows<false><<<8192, TPB, 0, stream>>>(xbuf, LFa, LFb, d_out);
}